// Round 7
// baseline (1108.801 us; speedup 1.0000x reference)
//
#include <hip/hip_runtime.h>

// GCN regressor: CSR-by-dst gather-reduce + LDS-tiled f32 GEMM.
// CSR build = hist -> scan -> binned 2-phase placement (stage + place),
// then 3x (GEMM -> fused gather/agg+bias+ReLU), pool fused into layer-3 agg,
// MLP head.
// k_agg: 2 half-waves gather 2 edges concurrently with float4 lanes (8 rows
// in flight per unrolled iter) -> latency hiding for the random L3 gather.

constexpr int HID = 128;
constexpr int BIN_SHIFT = 8;          // 256 dst nodes per bin
constexpr int MAXBINS = 512;

static __device__ __forceinline__ void fma4(float4& a, float s, const float4& b) {
    a.x += s * b.x; a.y += s * b.y; a.z += s * b.z; a.w += s * b.w;
}

// ---------------- CSR build ----------------
__global__ __launch_bounds__(256) void k_hist(const int* __restrict__ dst,
                                              int* __restrict__ cnt, int nE) {
    int i = blockIdx.x * 256 + threadIdx.x;
    if (i < nE) atomicAdd(&cnt[dst[i]], 1);
}

__global__ __launch_bounds__(256) void k_dinv(const int* __restrict__ cnt,
                                              float* __restrict__ dinv, int n) {
    int i = blockIdx.x * 256 + threadIdx.x;
    if (i < n) dinv[i] = rsqrtf((float)cnt[i] + 1.0f);  // +1 self-loop
}

// chunked exclusive scan: 1024 elems/block (256 thr x 4)
__global__ __launch_bounds__(256) void k_scan1(const int* __restrict__ cnt,
                                               int* __restrict__ offs,
                                               int* __restrict__ partials, int n) {
    __shared__ int lds[256];
    int tid = threadIdx.x;
    int base = blockIdx.x * 1024 + tid * 4;
    int a0 = (base + 0 < n) ? cnt[base + 0] : 0;
    int a1 = (base + 1 < n) ? cnt[base + 1] : 0;
    int a2 = (base + 2 < n) ? cnt[base + 2] : 0;
    int a3 = (base + 3 < n) ? cnt[base + 3] : 0;
    int s = a0 + a1 + a2 + a3;
    lds[tid] = s;
    __syncthreads();
    for (int off = 1; off < 256; off <<= 1) {
        int v = (tid >= off) ? lds[tid - off] : 0;
        __syncthreads();
        lds[tid] += v;
        __syncthreads();
    }
    int excl = lds[tid] - s;
    if (tid == 255) partials[blockIdx.x] = lds[255];
    if (base + 0 < n) offs[base + 0] = excl;
    if (base + 1 < n) offs[base + 1] = excl + a0;
    if (base + 2 < n) offs[base + 2] = excl + a0 + a1;
    if (base + 3 < n) offs[base + 3] = excl + a0 + a1 + a2;
}

__global__ void k_scan2(int* partials, int nP) {
    int run = 0;
    for (int i = 0; i < nP; ++i) { int t = partials[i]; partials[i] = run; run += t; }
}

__global__ __launch_bounds__(256) void k_scan3(int* __restrict__ offs,
                                               const int* __restrict__ partials,
                                               int n, int nE) {
    int i = blockIdx.x * 256 + threadIdx.x;
    if (i < n) offs[i] += partials[i >> 10];
    if (i == 0) offs[n] = nE;
}

__global__ __launch_bounds__(256) void k_bininit(const int* __restrict__ row_start,
                                                 int* __restrict__ bin_cursor,
                                                 int nbins, int nN) {
    int b = blockIdx.x * 256 + threadIdx.x;
    if (b < nbins) bin_cursor[b] = row_start[min(b << BIN_SHIFT, nN)];
}

// Phase 1: bin (src,dst) pairs into dst-range bins; per-WG span reservation
// keeps staged writes XCD-local and line-dense.
__global__ __launch_bounds__(256) void k_stage(const int* __restrict__ src,
                                               const int* __restrict__ dst,
                                               int* __restrict__ bin_cursor,
                                               int2* __restrict__ staged,
                                               int nE, int nbins) {
    __shared__ int hist[MAXBINS];
    __shared__ int wbase[MAXBINS];
    __shared__ int rank[MAXBINS];
    const int tid = threadIdx.x;
    const long long e0 = (long long)blockIdx.x * 4096;
    int es[16], ed[16];
#pragma unroll
    for (int k = 0; k < 16; ++k) {
        long long e = e0 + k * 256 + tid;
        if (e < nE) { es[k] = src[e]; ed[k] = dst[e]; }
        else        { es[k] = 0; ed[k] = -1; }
    }
    for (int t = tid; t < nbins; t += 256) { hist[t] = 0; rank[t] = 0; }
    __syncthreads();
#pragma unroll
    for (int k = 0; k < 16; ++k)
        if (ed[k] >= 0) atomicAdd(&hist[ed[k] >> BIN_SHIFT], 1);
    __syncthreads();
    for (int t = tid; t < nbins; t += 256)
        wbase[t] = hist[t] ? atomicAdd(&bin_cursor[t], hist[t]) : 0;
    __syncthreads();
#pragma unroll
    for (int k = 0; k < 16; ++k)
        if (ed[k] >= 0) {
            int b = ed[k] >> BIN_SHIFT;
            int r = atomicAdd(&rank[b], 1);
            staged[wbase[b] + r] = make_int2(es[k], ed[k]);
        }
}

// Phase 2: one WG per bin; LDS cursors hand out final CSR slots; all esrc
// writes fall in this WG's private region (no cross-XCD sharing).
__global__ __launch_bounds__(256) void k_place(const int* __restrict__ row_start,
                                               const int2* __restrict__ staged,
                                               int* __restrict__ esrc, int nN) {
    __shared__ int cur[1 << BIN_SHIFT];
    const int d0 = blockIdx.x << BIN_SHIFT;
    const int dend = min(d0 + (1 << BIN_SHIFT), nN);
    const int tid = threadIdx.x;
    int d = d0 + tid;
    cur[tid] = (d < dend) ? row_start[d] : 0;
    __syncthreads();
    const int p0 = row_start[d0];
    const int p1 = row_start[dend];
    for (int i = p0 + tid; i < p1; i += 256) {
        int2 pr = staged[i];
        int pos = atomicAdd(&cur[pr.y - d0], 1);
        esrc[pos] = pr.x;
    }
}

// ---------------- GEMM: C[n,128] = A[n,128] @ W[128,128] ----------------
// 64-row x 128-col block tile, K in 2 passes of 64. 256 threads, 4x8 micro-tile.
__global__ __launch_bounds__(256) void k_gemm2(const float* __restrict__ A,
                                               const float* __restrict__ W,
                                               float* __restrict__ C, int n) {
    __shared__ float As[64][68];
    __shared__ float Ws[64][128];
    const int tid = threadIdx.x;
    const int tc = tid & 15;
    const int tr = tid >> 4;
    const int row0 = blockIdx.x * 64;

    float4 acc0[4] = {}, acc1[4] = {};

    for (int pass = 0; pass < 2; ++pass) {
        const int kb = pass * 64;
        for (int it = 0; it < 4; ++it) {
            int flat = it * 256 + tid;
            int r = flat >> 4, k4 = flat & 15;
            int gr = row0 + r;
            float4 v = make_float4(0.f, 0.f, 0.f, 0.f);
            if (gr < n) v = *(const float4*)(A + (size_t)gr * HID + kb + k4 * 4);
            *(float4*)(&As[r][k4 * 4]) = v;
        }
        for (int it = 0; it < 8; ++it) {
            int flat = it * 256 + tid;
            int k = flat >> 5, c4 = flat & 31;
            *(float4*)(&Ws[k][c4 * 4]) = *(const float4*)(W + (size_t)(kb + k) * HID + c4 * 4);
        }
        __syncthreads();

#pragma unroll 2
        for (int k4 = 0; k4 < 16; ++k4) {
            float ar[4][4];
            *(float4*)&ar[0][0] = *(const float4*)(&As[tr * 4 + 0][k4 * 4]);
            *(float4*)&ar[1][0] = *(const float4*)(&As[tr * 4 + 1][k4 * 4]);
            *(float4*)&ar[2][0] = *(const float4*)(&As[tr * 4 + 2][k4 * 4]);
            *(float4*)&ar[3][0] = *(const float4*)(&As[tr * 4 + 3][k4 * 4]);
#pragma unroll
            for (int j = 0; j < 4; ++j) {
                float4 b0 = *(const float4*)(&Ws[k4 * 4 + j][tc * 4]);
                float4 b1 = *(const float4*)(&Ws[k4 * 4 + j][64 + tc * 4]);
#pragma unroll
                for (int i = 0; i < 4; ++i) {
                    fma4(acc0[i], ar[i][j], b0);
                    fma4(acc1[i], ar[i][j], b1);
                }
            }
        }
        __syncthreads();
    }

#pragma unroll
    for (int i = 0; i < 4; ++i) {
        int r = row0 + tr * 4 + i;
        if (r < n) {
            *(float4*)(C + (size_t)r * HID + tc * 4) = acc0[i];
            *(float4*)(C + (size_t)r * HID + 64 + tc * 4) = acc1[i];
        }
    }
}

// ---------------- fused gather-aggregate + bias + ReLU (+ optional pool) ---
// One wave per dst node. Half-wave h (32 lanes) gathers edge e+h with per-lane
// float4 (32 x 16B = full 512B row); 4x unroll -> 8 rows in flight. Halves
// merged via shfl_xor(32); lanes 0-31 finish self-loop+bias+relu+store.
__global__ __launch_bounds__(256) void k_agg(const int* __restrict__ row_start,
                                             const int* __restrict__ esrc,
                                             const float* __restrict__ dinv,
                                             const float* __restrict__ hw,
                                             const float* __restrict__ bias,
                                             float* __restrict__ out, int n,
                                             float* __restrict__ pool_sums,
                                             const int* __restrict__ batch) {
    int t = blockIdx.x * 256 + threadIdx.x;
    int node = t >> 6;
    if (node >= n) return;
    const int lane = t & 63;
    const int half = lane >> 5;      // 0: even edges, 1: odd edges
    const int c4 = (lane & 31) * 4;  // channel block (16B)
    int e0 = row_start[node], e1 = row_start[node + 1];
    float dd = dinv[node];
    float4 acc = make_float4(0.f, 0.f, 0.f, 0.f);
    int e = e0;
    for (; e + 8 <= e1; e += 8) {
#pragma unroll
        for (int k = 0; k < 4; ++k) {
            int s = esrc[e + 2 * k + half];
            float w = dinv[s];
            const float4 v = *(const float4*)(hw + (size_t)s * HID + c4);
            fma4(acc, w, v);
        }
    }
    for (; e + 2 <= e1; e += 2) {
        int s = esrc[e + half];
        float w = dinv[s];
        const float4 v = *(const float4*)(hw + (size_t)s * HID + c4);
        fma4(acc, w, v);
    }
    if (e < e1 && half == 0) {       // odd remainder: lower half only
        int s = esrc[e];
        float w = dinv[s];
        const float4 v = *(const float4*)(hw + (size_t)s * HID + c4);
        fma4(acc, w, v);
    }
    // merge the two half-wave partials (lane i <-> lane i+32)
    acc.x += __shfl_xor(acc.x, 32);
    acc.y += __shfl_xor(acc.y, 32);
    acc.z += __shfl_xor(acc.z, 32);
    acc.w += __shfl_xor(acc.w, 32);
    if (half == 0) {
        const float4 hv = *(const float4*)(hw + (size_t)node * HID + c4);
        const float4 bv = *(const float4*)(bias + c4);
        float4 o;
        o.x = fmaxf(acc.x * dd + hv.x * dd * dd + bv.x, 0.f);
        o.y = fmaxf(acc.y * dd + hv.y * dd * dd + bv.y, 0.f);
        o.z = fmaxf(acc.z * dd + hv.z * dd * dd + bv.z, 0.f);
        o.w = fmaxf(acc.w * dd + hv.w * dd * dd + bv.w, 0.f);
        if (pool_sums) {
            float* p = &pool_sums[(size_t)batch[node] * HID + c4];
            atomicAdd(p + 0, o.x);
            atomicAdd(p + 1, o.y);
            atomicAdd(p + 2, o.z);
            atomicAdd(p + 3, o.w);
        } else {
            *(float4*)(out + (size_t)node * HID + c4) = o;
        }
    }
}

// ---------------- pooling / head ----------------
__global__ __launch_bounds__(256) void k_count(const int* __restrict__ batch,
                                               float* __restrict__ cnt, int n) {
    int i = blockIdx.x * 256 + threadIdx.x;
    if (i < n) atomicAdd(&cnt[batch[i]], 1.0f);
}

__global__ __launch_bounds__(64) void k_mlp(const float* __restrict__ sums,
                                            const float* __restrict__ cnt,
                                            const float* __restrict__ lw1,
                                            const float* __restrict__ lb1,
                                            const float* __restrict__ lw2,
                                            const float* __restrict__ lb2,
                                            float* __restrict__ out) {
    int g = blockIdx.x;
    int j = threadIdx.x;
    float inv = 1.0f / fmaxf(cnt[g], 1.0f);
    const float* srow = sums + (size_t)g * HID;
    float acc = lb1[j];
#pragma unroll 8
    for (int k = 0; k < HID; ++k) acc += srow[k] * inv * lw1[k * 64 + j];
    acc = fmaxf(acc, 0.0f);
    float prod = acc * lw2[j];
#pragma unroll
    for (int off = 32; off > 0; off >>= 1) prod += __shfl_down(prod, off);
    if (j == 0) out[g] = prod + lb2[0];
}

// ---------------- legacy fallbacks ----------------
__global__ __launch_bounds__(256) void k_bucket(const int* __restrict__ src,
                                                const int* __restrict__ dst,
                                                int* __restrict__ cursor,
                                                int* __restrict__ esrc, int nE) {
    int e = blockIdx.x * 256 + threadIdx.x;
    if (e >= nE) return;
    int pos = atomicAdd(&cursor[dst[e]], 1);
    esrc[pos] = src[e];
}

__global__ __launch_bounds__(256) void k_scatter(const int* __restrict__ src,
                                                 const int* __restrict__ dst,
                                                 const float* __restrict__ dinv,
                                                 const float* __restrict__ hw,
                                                 float* __restrict__ agg, int nE) {
    long long t = (long long)blockIdx.x * 256 + threadIdx.x;
    int e = (int)(t >> 6);
    if (e >= nE) return;
    int c = ((int)t & 63) * 2;
    int s = src[e], d = dst[e];
    float w = dinv[s] * dinv[d];
    const float2 v = *(const float2*)(hw + (size_t)s * HID + c);
    float* p = agg + (size_t)d * HID + c;
    atomicAdd(p, v.x * w);
    atomicAdd(p + 1, v.y * w);
}

__global__ __launch_bounds__(256) void k_fuse(const float* __restrict__ agg,
                                              const float* hw,
                                              const float* __restrict__ dinv,
                                              const float* __restrict__ b,
                                              float* out, int n) {
    int t = blockIdx.x * 256 + threadIdx.x;
    if (t >= n * HID) return;
    int node = t >> 7, c = t & (HID - 1);
    float di = dinv[node];
    float v = agg[t] + hw[t] * di * di + b[c];
    out[t] = fmaxf(v, 0.0f);
}

__global__ __launch_bounds__(256) void k_poolsum(const int* __restrict__ batch,
                                                 const float* __restrict__ h,
                                                 float* __restrict__ sums, int n) {
    int t = blockIdx.x * 256 + threadIdx.x;
    if (t >= n * HID) return;
    int node = t >> 7, c = t & (HID - 1);
    atomicAdd(&sums[(size_t)batch[node] * HID + c], h[t]);
}

extern "C" void kernel_launch(void* const* d_in, const int* in_sizes, int n_in,
                              void* d_out, int out_size, void* d_ws, size_t ws_size,
                              hipStream_t stream) {
    const float* x   = (const float*)d_in[0];
    const int*   ei  = (const int*)d_in[1];
    const int*   bat = (const int*)d_in[2];
    const float* W1  = (const float*)d_in[3];
    const float* b1  = (const float*)d_in[4];
    const float* W2  = (const float*)d_in[5];
    const float* b2  = (const float*)d_in[6];
    const float* W3  = (const float*)d_in[7];
    const float* b3  = (const float*)d_in[8];
    const float* lw1 = (const float*)d_in[9];
    const float* lb1 = (const float*)d_in[10];
    const float* lw2 = (const float*)d_in[11];
    const float* lb2 = (const float*)d_in[12];
    float* out = (float*)d_out;

    const int nN = in_sizes[2];       // 100000
    const int nE = in_sizes[1] / 2;   // 3200000
    const int G  = out_size;          // 4096
    const int* src = ei;
    const int* dst = ei + nE;

    const int nP = (nN + 1023) / 1024;
    const int nbins = (nN + (1 << BIN_SHIFT) - 1) >> BIN_SHIFT;

    // workspace layout
    char* p = (char*)d_ws;
    auto alloc = [&](size_t bytes) { char* r = p; p += (bytes + 255) & ~(size_t)255; return r; };
    float* buf0      = (float*)alloc(sizeof(float) * (size_t)nN * HID);
    float* buf1      = (float*)alloc(sizeof(float) * (size_t)nN * HID);
    float* dinv      = (float*)alloc(sizeof(float) * nN);
    float* sums      = (float*)alloc(sizeof(float) * (size_t)G * HID);
    float* cnt       = (float*)alloc(sizeof(float) * G);
    int*   cnt_int   = (int*)alloc(sizeof(int) * nN);
    int*   row_start = (int*)alloc(sizeof(int) * (nN + 1));
    int*   cursor    = (int*)alloc(sizeof(int) * nN);   // also bin_cursor (first nbins ints)
    int*   partials  = (int*)alloc(sizeof(int) * (nP + 1));
    int*   esrc      = (int*)alloc(sizeof(int) * (size_t)nE);
    size_t full_need = (size_t)(p - (char*)d_ws);
    int2*  staged    = (int2*)buf1;   // aliases buf1: consumed before agg writes buf1

    const int gemmGrid = (nN + 63) / 64;
    const int aggGrid  = (int)(((long long)nN * 64 + 255) / 256);

    hipMemsetAsync(cnt_int, 0, sizeof(int) * nN, stream);
    k_hist<<<(nE + 255) / 256, 256, 0, stream>>>(dst, cnt_int, nE);
    k_dinv<<<(nN + 255) / 256, 256, 0, stream>>>(cnt_int, dinv, nN);

    if (ws_size >= full_need) {
        // ---- CSR gather path ----
        k_scan1<<<nP, 256, 0, stream>>>(cnt_int, row_start, partials, nN);
        k_scan2<<<1, 1, 0, stream>>>(partials, nP);
        k_scan3<<<(nN + 255) / 256, 256, 0, stream>>>(row_start, partials, nN, nE);

        if (nbins <= MAXBINS) {
            k_bininit<<<(nbins + 255) / 256, 256, 0, stream>>>(row_start, cursor, nbins, nN);
            k_stage<<<(int)(((long long)nE + 4095) / 4096), 256, 0, stream>>>(src, dst, cursor, staged, nE, nbins);
            k_place<<<nbins, 256, 0, stream>>>(row_start, staged, esrc, nN);
        } else {
            // cursor must hold row_start values
            hipMemcpyAsync(cursor, row_start, sizeof(int) * nN, hipMemcpyDeviceToDevice, stream);
            k_bucket<<<(nE + 255) / 256, 256, 0, stream>>>(src, dst, cursor, esrc, nE);
        }

        hipMemsetAsync(sums, 0, sizeof(float) * ((size_t)G * HID + G), stream);
        k_count<<<(nN + 255) / 256, 256, 0, stream>>>(bat, cnt, nN);

        k_gemm2<<<gemmGrid, 256, 0, stream>>>(x, W1, buf0, nN);
        k_agg<<<aggGrid, 256, 0, stream>>>(row_start, esrc, dinv, buf0, b1, buf1, nN, nullptr, nullptr);
        k_gemm2<<<gemmGrid, 256, 0, stream>>>(buf1, W2, buf0, nN);
        k_agg<<<aggGrid, 256, 0, stream>>>(row_start, esrc, dinv, buf0, b2, buf1, nN, nullptr, nullptr);
        k_gemm2<<<gemmGrid, 256, 0, stream>>>(buf1, W3, buf0, nN);
        k_agg<<<aggGrid, 256, 0, stream>>>(row_start, esrc, dinv, buf0, b3, nullptr, nN, sums, bat);
    } else {
        // ---- legacy atomic path ----
        const int elemGrid = (nN * HID + 255) / 256;
        const int scatGrid = (int)(((long long)nE * 64 + 255) / 256);
        const size_t hbytes = sizeof(float) * (size_t)nN * HID;

        k_gemm2<<<gemmGrid, 256, 0, stream>>>(x, W1, buf0, nN);
        hipMemsetAsync(buf1, 0, hbytes, stream);
        k_scatter<<<scatGrid, 256, 0, stream>>>(src, dst, dinv, buf0, buf1, nE);
        k_fuse<<<elemGrid, 256, 0, stream>>>(buf1, buf0, dinv, b1, buf0, nN);

        k_gemm2<<<gemmGrid, 256, 0, stream>>>(buf0, W2, buf1, nN);
        hipMemsetAsync(buf0, 0, hbytes, stream);
        k_scatter<<<scatGrid, 256, 0, stream>>>(src, dst, dinv, buf1, buf0, nE);
        k_fuse<<<elemGrid, 256, 0, stream>>>(buf0, buf1, dinv, b2, buf1, nN);

        k_gemm2<<<gemmGrid, 256, 0, stream>>>(buf1, W3, buf0, nN);
        hipMemsetAsync(buf1, 0, hbytes, stream);
        k_scatter<<<scatGrid, 256, 0, stream>>>(src, dst, dinv, buf0, buf1, nE);
        k_fuse<<<elemGrid, 256, 0, stream>>>(buf1, buf0, dinv, b3, buf0, nN);

        hipMemsetAsync(sums, 0, sizeof(float) * ((size_t)G * HID + G), stream);
        k_count<<<(nN + 255) / 256, 256, 0, stream>>>(bat, cnt, nN);
        k_poolsum<<<elemGrid, 256, 0, stream>>>(bat, buf0, sums, nN);
    }

    k_mlp<<<G, 64, 0, stream>>>(sums, cnt, lw1, lb1, lw2, lb2, out);
}

// Round 8
// 756.796 us; speedup vs baseline: 1.4651x; 1.4651x over previous
//
#include <hip/hip_runtime.h>

// GCN regressor: CSR-by-dst gather-reduce, bf16 gather rows pre-scaled by
// dinv[src] (folds symmetric norm + self-loop into one sum), LDS-tiled GEMM.
// CSR build = hist -> scan -> binned 2-phase placement (stage + place).

constexpr int HID = 128;
constexpr int BIN_SHIFT = 8;          // 256 dst nodes per bin
constexpr int MAXBINS = 512;

static __device__ __forceinline__ void fma4(float4& a, float s, const float4& b) {
    a.x += s * b.x; a.y += s * b.y; a.z += s * b.z; a.w += s * b.w;
}
static __device__ __forceinline__ unsigned bf16rne(float f) {
    unsigned u = __float_as_uint(f);
    return (u + 0x7FFFu + ((u >> 16) & 1u)) >> 16;
}
static __device__ __forceinline__ unsigned packbf16(float lo, float hi) {
    return bf16rne(lo) | (bf16rne(hi) << 16);
}
static __device__ __forceinline__ float blo(unsigned u) { return __uint_as_float(u << 16); }
static __device__ __forceinline__ float bhi(unsigned u) { return __uint_as_float(u & 0xFFFF0000u); }

// ---------------- CSR build ----------------
__global__ __launch_bounds__(256) void k_hist(const int* __restrict__ dst,
                                              int* __restrict__ cnt, int nE) {
    int i = blockIdx.x * 256 + threadIdx.x;
    if (i < nE) atomicAdd(&cnt[dst[i]], 1);
}

__global__ __launch_bounds__(256) void k_dinv(const int* __restrict__ cnt,
                                              float* __restrict__ dinv, int n) {
    int i = blockIdx.x * 256 + threadIdx.x;
    if (i < n) dinv[i] = rsqrtf((float)cnt[i] + 1.0f);  // +1 self-loop
}

__global__ __launch_bounds__(256) void k_scan1(const int* __restrict__ cnt,
                                               int* __restrict__ offs,
                                               int* __restrict__ partials, int n) {
    __shared__ int lds[256];
    int tid = threadIdx.x;
    int base = blockIdx.x * 1024 + tid * 4;
    int a0 = (base + 0 < n) ? cnt[base + 0] : 0;
    int a1 = (base + 1 < n) ? cnt[base + 1] : 0;
    int a2 = (base + 2 < n) ? cnt[base + 2] : 0;
    int a3 = (base + 3 < n) ? cnt[base + 3] : 0;
    int s = a0 + a1 + a2 + a3;
    lds[tid] = s;
    __syncthreads();
    for (int off = 1; off < 256; off <<= 1) {
        int v = (tid >= off) ? lds[tid - off] : 0;
        __syncthreads();
        lds[tid] += v;
        __syncthreads();
    }
    int excl = lds[tid] - s;
    if (tid == 255) partials[blockIdx.x] = lds[255];
    if (base + 0 < n) offs[base + 0] = excl;
    if (base + 1 < n) offs[base + 1] = excl + a0;
    if (base + 2 < n) offs[base + 2] = excl + a0 + a1;
    if (base + 3 < n) offs[base + 3] = excl + a0 + a1 + a2;
}

__global__ void k_scan2(int* partials, int nP) {
    int run = 0;
    for (int i = 0; i < nP; ++i) { int t = partials[i]; partials[i] = run; run += t; }
}

__global__ __launch_bounds__(256) void k_scan3(int* __restrict__ offs,
                                               const int* __restrict__ partials,
                                               int n, int nE) {
    int i = blockIdx.x * 256 + threadIdx.x;
    if (i < n) offs[i] += partials[i >> 10];
    if (i == 0) offs[n] = nE;
}

__global__ __launch_bounds__(256) void k_bininit(const int* __restrict__ row_start,
                                                 int* __restrict__ bin_cursor,
                                                 int nbins, int nN) {
    int b = blockIdx.x * 256 + threadIdx.x;
    if (b < nbins) bin_cursor[b] = row_start[min(b << BIN_SHIFT, nN)];
}

__global__ __launch_bounds__(256) void k_stage(const int* __restrict__ src,
                                               const int* __restrict__ dst,
                                               int* __restrict__ bin_cursor,
                                               int2* __restrict__ staged,
                                               int nE, int nbins) {
    __shared__ int hist[MAXBINS];
    __shared__ int wbase[MAXBINS];
    __shared__ int rank[MAXBINS];
    const int tid = threadIdx.x;
    const long long e0 = (long long)blockIdx.x * 4096;
    int es[16], ed[16];
#pragma unroll
    for (int k = 0; k < 16; ++k) {
        long long e = e0 + k * 256 + tid;
        if (e < nE) { es[k] = src[e]; ed[k] = dst[e]; }
        else        { es[k] = 0; ed[k] = -1; }
    }
    for (int t = tid; t < nbins; t += 256) { hist[t] = 0; rank[t] = 0; }
    __syncthreads();
#pragma unroll
    for (int k = 0; k < 16; ++k)
        if (ed[k] >= 0) atomicAdd(&hist[ed[k] >> BIN_SHIFT], 1);
    __syncthreads();
    for (int t = tid; t < nbins; t += 256)
        wbase[t] = hist[t] ? atomicAdd(&bin_cursor[t], hist[t]) : 0;
    __syncthreads();
#pragma unroll
    for (int k = 0; k < 16; ++k)
        if (ed[k] >= 0) {
            int b = ed[k] >> BIN_SHIFT;
            int r = atomicAdd(&rank[b], 1);
            staged[wbase[b] + r] = make_int2(es[k], ed[k]);
        }
}

__global__ __launch_bounds__(256) void k_place(const int* __restrict__ row_start,
                                               const int2* __restrict__ staged,
                                               int* __restrict__ esrc, int nN) {
    __shared__ int cur[1 << BIN_SHIFT];
    const int d0 = blockIdx.x << BIN_SHIFT;
    const int dend = min(d0 + (1 << BIN_SHIFT), nN);
    const int tid = threadIdx.x;
    int d = d0 + tid;
    cur[tid] = (d < dend) ? row_start[d] : 0;
    __syncthreads();
    const int p0 = row_start[d0];
    const int p1 = row_start[dend];
    for (int i = p0 + tid; i < p1; i += 256) {
        int2 pr = staged[i];
        int pos = atomicAdd(&cur[pr.y - d0], 1);
        esrc[pos] = pr.x;
    }
}

// ---------------- GEMM -> bf16 rows scaled by dinv[row] ----------------
// h16[r][c] = bf16( (A[r,:]@W[:,c]) * dinv[r] ).  64-row x 128-col tile.
__global__ __launch_bounds__(256) void k_gemm3(const float* __restrict__ A,
                                               const float* __restrict__ W,
                                               const float* __restrict__ dinv,
                                               unsigned* __restrict__ h16, int n) {
    __shared__ float As[64][68];
    __shared__ float Ws[64][128];
    const int tid = threadIdx.x;
    const int tc = tid & 15;
    const int tr = tid >> 4;
    const int row0 = blockIdx.x * 64;

    float4 acc0[4] = {}, acc1[4] = {};

    for (int pass = 0; pass < 2; ++pass) {
        const int kb = pass * 64;
        for (int it = 0; it < 4; ++it) {
            int flat = it * 256 + tid;
            int r = flat >> 4, k4 = flat & 15;
            int gr = row0 + r;
            float4 v = make_float4(0.f, 0.f, 0.f, 0.f);
            if (gr < n) v = *(const float4*)(A + (size_t)gr * HID + kb + k4 * 4);
            *(float4*)(&As[r][k4 * 4]) = v;
        }
        for (int it = 0; it < 8; ++it) {
            int flat = it * 256 + tid;
            int k = flat >> 5, c4 = flat & 31;
            *(float4*)(&Ws[k][c4 * 4]) = *(const float4*)(W + (size_t)(kb + k) * HID + c4 * 4);
        }
        __syncthreads();

#pragma unroll 2
        for (int k4 = 0; k4 < 16; ++k4) {
            float ar[4][4];
            *(float4*)&ar[0][0] = *(const float4*)(&As[tr * 4 + 0][k4 * 4]);
            *(float4*)&ar[1][0] = *(const float4*)(&As[tr * 4 + 1][k4 * 4]);
            *(float4*)&ar[2][0] = *(const float4*)(&As[tr * 4 + 2][k4 * 4]);
            *(float4*)&ar[3][0] = *(const float4*)(&As[tr * 4 + 3][k4 * 4]);
#pragma unroll
            for (int j = 0; j < 4; ++j) {
                float4 b0 = *(const float4*)(&Ws[k4 * 4 + j][tc * 4]);
                float4 b1 = *(const float4*)(&Ws[k4 * 4 + j][64 + tc * 4]);
#pragma unroll
                for (int i = 0; i < 4; ++i) {
                    fma4(acc0[i], ar[i][j], b0);
                    fma4(acc1[i], ar[i][j], b1);
                }
            }
        }
        __syncthreads();
    }

#pragma unroll
    for (int i = 0; i < 4; ++i) {
        int r = row0 + tr * 4 + i;
        if (r < n) {
            float di = dinv[r];
            float4 a0 = acc0[i], a1 = acc1[i];
            uint2 p0, p1;
            p0.x = packbf16(a0.x * di, a0.y * di);
            p0.y = packbf16(a0.z * di, a0.w * di);
            p1.x = packbf16(a1.x * di, a1.y * di);
            p1.y = packbf16(a1.z * di, a1.w * di);
            *(uint2*)(h16 + (size_t)r * 64 + tc * 2) = p0;
            *(uint2*)(h16 + (size_t)r * 64 + 32 + tc * 2) = p1;
        }
    }
}

// ---------------- fused gather-aggregate + bias + ReLU (+ optional pool) ---
// One wave per dst node; lane owns 2 channels (one u32 = 2 bf16). Rows are
// pre-scaled by dinv[src], so out = relu(dd * (sum_nbr + self) + b).
__global__ __launch_bounds__(256) void k_agg16(const int* __restrict__ row_start,
                                               const int* __restrict__ esrc,
                                               const float* __restrict__ dinv,
                                               const unsigned* __restrict__ h16,
                                               const float* __restrict__ bias,
                                               float* __restrict__ out, int n,
                                               float* __restrict__ pool_sums,
                                               const int* __restrict__ batch) {
    int t = blockIdx.x * 256 + threadIdx.x;
    int node = t >> 6;
    if (node >= n) return;
    const int lane = t & 63;
    int e0 = row_start[node], e1 = row_start[node + 1];
    e0 = __builtin_amdgcn_readfirstlane(e0);
    e1 = __builtin_amdgcn_readfirstlane(e1);
    float dd = dinv[node];

    unsigned su = h16[(size_t)node * 64 + lane];   // self row (pre-scaled)
    float ax = blo(su), ay = bhi(su);

    int e = e0;
    for (; e + 4 <= e1; e += 4) {
        int s0 = __builtin_amdgcn_readfirstlane(esrc[e + 0]);
        int s1 = __builtin_amdgcn_readfirstlane(esrc[e + 1]);
        int s2 = __builtin_amdgcn_readfirstlane(esrc[e + 2]);
        int s3 = __builtin_amdgcn_readfirstlane(esrc[e + 3]);
        unsigned u0 = h16[(size_t)s0 * 64 + lane];
        unsigned u1 = h16[(size_t)s1 * 64 + lane];
        unsigned u2 = h16[(size_t)s2 * 64 + lane];
        unsigned u3 = h16[(size_t)s3 * 64 + lane];
        ax += blo(u0) + blo(u1) + blo(u2) + blo(u3);
        ay += bhi(u0) + bhi(u1) + bhi(u2) + bhi(u3);
    }
    for (; e < e1; ++e) {
        int s = __builtin_amdgcn_readfirstlane(esrc[e]);
        unsigned u = h16[(size_t)s * 64 + lane];
        ax += blo(u);
        ay += bhi(u);
    }

    const float2 bv = *(const float2*)(bias + 2 * lane);
    float ox = fmaxf(ax * dd + bv.x, 0.f);
    float oy = fmaxf(ay * dd + bv.y, 0.f);
    if (pool_sums) {
        float* p = &pool_sums[(size_t)batch[node] * HID + 2 * lane];
        atomicAdd(p, ox);
        atomicAdd(p + 1, oy);
    } else {
        *(float2*)(out + (size_t)node * HID + 2 * lane) = make_float2(ox, oy);
    }
}

// ---------------- pooling / head ----------------
__global__ __launch_bounds__(256) void k_count(const int* __restrict__ batch,
                                               float* __restrict__ cnt, int n) {
    int i = blockIdx.x * 256 + threadIdx.x;
    if (i < n) atomicAdd(&cnt[batch[i]], 1.0f);
}

__global__ __launch_bounds__(64) void k_mlp(const float* __restrict__ sums,
                                            const float* __restrict__ cnt,
                                            const float* __restrict__ lw1,
                                            const float* __restrict__ lb1,
                                            const float* __restrict__ lw2,
                                            const float* __restrict__ lb2,
                                            float* __restrict__ out) {
    int g = blockIdx.x;
    int j = threadIdx.x;
    float inv = 1.0f / fmaxf(cnt[g], 1.0f);
    const float* srow = sums + (size_t)g * HID;
    float acc = lb1[j];
#pragma unroll 8
    for (int k = 0; k < HID; ++k) acc += srow[k] * inv * lw1[k * 64 + j];
    acc = fmaxf(acc, 0.0f);
    float prod = acc * lw2[j];
#pragma unroll
    for (int off = 32; off > 0; off >>= 1) prod += __shfl_down(prod, off);
    if (j == 0) out[g] = prod + lb2[0];
}

// ---------------- legacy fallbacks (f32 path) ----------------
__global__ __launch_bounds__(256) void k_gemm2(const float* __restrict__ A,
                                               const float* __restrict__ W,
                                               float* __restrict__ C, int n) {
    __shared__ float As[64][68];
    __shared__ float Ws[64][128];
    const int tid = threadIdx.x;
    const int tc = tid & 15;
    const int tr = tid >> 4;
    const int row0 = blockIdx.x * 64;
    float4 acc0[4] = {}, acc1[4] = {};
    for (int pass = 0; pass < 2; ++pass) {
        const int kb = pass * 64;
        for (int it = 0; it < 4; ++it) {
            int flat = it * 256 + tid;
            int r = flat >> 4, k4 = flat & 15;
            int gr = row0 + r;
            float4 v = make_float4(0.f, 0.f, 0.f, 0.f);
            if (gr < n) v = *(const float4*)(A + (size_t)gr * HID + kb + k4 * 4);
            *(float4*)(&As[r][k4 * 4]) = v;
        }
        for (int it = 0; it < 8; ++it) {
            int flat = it * 256 + tid;
            int k = flat >> 5, c4 = flat & 31;
            *(float4*)(&Ws[k][c4 * 4]) = *(const float4*)(W + (size_t)(kb + k) * HID + c4 * 4);
        }
        __syncthreads();
#pragma unroll 2
        for (int k4 = 0; k4 < 16; ++k4) {
            float ar[4][4];
            *(float4*)&ar[0][0] = *(const float4*)(&As[tr * 4 + 0][k4 * 4]);
            *(float4*)&ar[1][0] = *(const float4*)(&As[tr * 4 + 1][k4 * 4]);
            *(float4*)&ar[2][0] = *(const float4*)(&As[tr * 4 + 2][k4 * 4]);
            *(float4*)&ar[3][0] = *(const float4*)(&As[tr * 4 + 3][k4 * 4]);
#pragma unroll
            for (int j = 0; j < 4; ++j) {
                float4 b0 = *(const float4*)(&Ws[k4 * 4 + j][tc * 4]);
                float4 b1 = *(const float4*)(&Ws[k4 * 4 + j][64 + tc * 4]);
#pragma unroll
                for (int i = 0; i < 4; ++i) {
                    fma4(acc0[i], ar[i][j], b0);
                    fma4(acc1[i], ar[i][j], b1);
                }
            }
        }
        __syncthreads();
    }
#pragma unroll
    for (int i = 0; i < 4; ++i) {
        int r = row0 + tr * 4 + i;
        if (r < n) {
            *(float4*)(C + (size_t)r * HID + tc * 4) = acc0[i];
            *(float4*)(C + (size_t)r * HID + 64 + tc * 4) = acc1[i];
        }
    }
}

__global__ __launch_bounds__(256) void k_bucket(const int* __restrict__ src,
                                                const int* __restrict__ dst,
                                                int* __restrict__ cursor,
                                                int* __restrict__ esrc, int nE) {
    int e = blockIdx.x * 256 + threadIdx.x;
    if (e >= nE) return;
    int pos = atomicAdd(&cursor[dst[e]], 1);
    esrc[pos] = src[e];
}

__global__ __launch_bounds__(256) void k_scatter(const int* __restrict__ src,
                                                 const int* __restrict__ dst,
                                                 const float* __restrict__ dinv,
                                                 const float* __restrict__ hw,
                                                 float* __restrict__ agg, int nE) {
    long long t = (long long)blockIdx.x * 256 + threadIdx.x;
    int e = (int)(t >> 6);
    if (e >= nE) return;
    int c = ((int)t & 63) * 2;
    int s = src[e], d = dst[e];
    float w = dinv[s] * dinv[d];
    const float2 v = *(const float2*)(hw + (size_t)s * HID + c);
    float* p = agg + (size_t)d * HID + c;
    atomicAdd(p, v.x * w);
    atomicAdd(p + 1, v.y * w);
}

__global__ __launch_bounds__(256) void k_fuse(const float* __restrict__ agg,
                                              const float* hw,
                                              const float* __restrict__ dinv,
                                              const float* __restrict__ b,
                                              float* out, int n) {
    int t = blockIdx.x * 256 + threadIdx.x;
    if (t >= n * HID) return;
    int node = t >> 7, c = t & (HID - 1);
    float di = dinv[node];
    float v = agg[t] + hw[t] * di * di + b[c];
    out[t] = fmaxf(v, 0.0f);
}

__global__ __launch_bounds__(256) void k_poolsum(const int* __restrict__ batch,
                                                 const float* __restrict__ h,
                                                 float* __restrict__ sums, int n) {
    int t = blockIdx.x * 256 + threadIdx.x;
    if (t >= n * HID) return;
    int node = t >> 7, c = t & (HID - 1);
    atomicAdd(&sums[(size_t)batch[node] * HID + c], h[t]);
}

extern "C" void kernel_launch(void* const* d_in, const int* in_sizes, int n_in,
                              void* d_out, int out_size, void* d_ws, size_t ws_size,
                              hipStream_t stream) {
    const float* x   = (const float*)d_in[0];
    const int*   ei  = (const int*)d_in[1];
    const int*   bat = (const int*)d_in[2];
    const float* W1  = (const float*)d_in[3];
    const float* b1  = (const float*)d_in[4];
    const float* W2  = (const float*)d_in[5];
    const float* b2  = (const float*)d_in[6];
    const float* W3  = (const float*)d_in[7];
    const float* b3  = (const float*)d_in[8];
    const float* lw1 = (const float*)d_in[9];
    const float* lb1 = (const float*)d_in[10];
    const float* lw2 = (const float*)d_in[11];
    const float* lb2 = (const float*)d_in[12];
    float* out = (float*)d_out;

    const int nN = in_sizes[2];       // 100000
    const int nE = in_sizes[1] / 2;   // 3200000
    const int G  = out_size;          // 4096
    const int* src = ei;
    const int* dst = ei + nE;

    const int nP = (nN + 1023) / 1024;
    const int nbins = (nN + (1 << BIN_SHIFT) - 1) >> BIN_SHIFT;

    // workspace layout
    char* p = (char*)d_ws;
    auto alloc = [&](size_t bytes) { char* r = p; p += (bytes + 255) & ~(size_t)255; return r; };
    float* buf0      = (float*)alloc(sizeof(float) * (size_t)nN * HID);
    float* buf1      = (float*)alloc(sizeof(float) * (size_t)nN * HID);
    float* dinv      = (float*)alloc(sizeof(float) * nN);
    float* sums      = (float*)alloc(sizeof(float) * (size_t)G * HID);
    float* cnt       = (float*)alloc(sizeof(float) * G);
    int*   cnt_int   = (int*)alloc(sizeof(int) * nN);
    int*   row_start = (int*)alloc(sizeof(int) * (nN + 1));
    int*   cursor    = (int*)alloc(sizeof(int) * nN);   // also bin_cursor
    int*   partials  = (int*)alloc(sizeof(int) * (nP + 1));
    int*   esrc      = (int*)alloc(sizeof(int) * (size_t)nE);
    size_t full_need = (size_t)(p - (char*)d_ws);
    int2*     staged = (int2*)buf1;      // consumed by k_place before gemm writes h16
    unsigned* h16    = (unsigned*)buf1;  // bf16 rows (nN x 64 u32 = 25.6 MB) in buf1

    const int gemmGrid = (nN + 63) / 64;
    const int aggGrid  = (int)(((long long)nN * 64 + 255) / 256);

    hipMemsetAsync(cnt_int, 0, sizeof(int) * nN, stream);
    k_hist<<<(nE + 255) / 256, 256, 0, stream>>>(dst, cnt_int, nE);
    k_dinv<<<(nN + 255) / 256, 256, 0, stream>>>(cnt_int, dinv, nN);

    if (ws_size >= full_need) {
        // ---- CSR gather path ----
        k_scan1<<<nP, 256, 0, stream>>>(cnt_int, row_start, partials, nN);
        k_scan2<<<1, 1, 0, stream>>>(partials, nP);
        k_scan3<<<(nN + 255) / 256, 256, 0, stream>>>(row_start, partials, nN, nE);

        if (nbins <= MAXBINS) {
            k_bininit<<<(nbins + 255) / 256, 256, 0, stream>>>(row_start, cursor, nbins, nN);
            k_stage<<<(int)(((long long)nE + 4095) / 4096), 256, 0, stream>>>(src, dst, cursor, staged, nE, nbins);
            k_place<<<nbins, 256, 0, stream>>>(row_start, staged, esrc, nN);
        } else {
            hipMemcpyAsync(cursor, row_start, sizeof(int) * nN, hipMemcpyDeviceToDevice, stream);
            k_bucket<<<(nE + 255) / 256, 256, 0, stream>>>(src, dst, cursor, esrc, nE);
        }

        hipMemsetAsync(sums, 0, sizeof(float) * ((size_t)G * HID + G), stream);
        k_count<<<(nN + 255) / 256, 256, 0, stream>>>(bat, cnt, nN);

        // layer i: gemm3(in f32 -> h16 bf16, scaled by dinv) ; agg16(h16 -> out f32)
        k_gemm3<<<gemmGrid, 256, 0, stream>>>(x, W1, dinv, h16, nN);
        k_agg16<<<aggGrid, 256, 0, stream>>>(row_start, esrc, dinv, h16, b1, buf0, nN, nullptr, nullptr);
        k_gemm3<<<gemmGrid, 256, 0, stream>>>(buf0, W2, dinv, h16, nN);
        k_agg16<<<aggGrid, 256, 0, stream>>>(row_start, esrc, dinv, h16, b2, buf0, nN, nullptr, nullptr);
        k_gemm3<<<gemmGrid, 256, 0, stream>>>(buf0, W3, dinv, h16, nN);
        k_agg16<<<aggGrid, 256, 0, stream>>>(row_start, esrc, dinv, h16, b3, nullptr, nN, sums, bat);
    } else {
        // ---- legacy atomic path ----
        const int elemGrid = (nN * HID + 255) / 256;
        const int scatGrid = (int)(((long long)nE * 64 + 255) / 256);
        const size_t hbytes = sizeof(float) * (size_t)nN * HID;

        k_gemm2<<<gemmGrid, 256, 0, stream>>>(x, W1, buf0, nN);
        hipMemsetAsync(buf1, 0, hbytes, stream);
        k_scatter<<<scatGrid, 256, 0, stream>>>(src, dst, dinv, buf0, buf1, nE);
        k_fuse<<<elemGrid, 256, 0, stream>>>(buf1, buf0, dinv, b1, buf0, nN);

        k_gemm2<<<gemmGrid, 256, 0, stream>>>(buf0, W2, buf1, nN);
        hipMemsetAsync(buf0, 0, hbytes, stream);
        k_scatter<<<scatGrid, 256, 0, stream>>>(src, dst, dinv, buf1, buf0, nE);
        k_fuse<<<elemGrid, 256, 0, stream>>>(buf0, buf1, dinv, b2, buf1, nN);

        k_gemm2<<<gemmGrid, 256, 0, stream>>>(buf1, W3, buf0, nN);
        hipMemsetAsync(buf1, 0, hbytes, stream);
        k_scatter<<<scatGrid, 256, 0, stream>>>(src, dst, dinv, buf0, buf1, nE);
        k_fuse<<<elemGrid, 256, 0, stream>>>(buf1, buf0, dinv, b3, buf0, nN);

        hipMemsetAsync(sums, 0, sizeof(float) * ((size_t)G * HID + G), stream);
        k_count<<<(nN + 255) / 256, 256, 0, stream>>>(bat, cnt, nN);
        k_poolsum<<<elemGrid, 256, 0, stream>>>(bat, buf0, sums, nN);
    }

    k_mlp<<<G, 64, 0, stream>>>(sums, cnt, lw1, lb1, lw2, lb2, out);
}

// Round 9
// 635.820 us; speedup vs baseline: 1.7439x; 1.1903x over previous
//
#include <hip/hip_runtime.h>

// GCN regressor, round 9:
//  - CSR build fully binned: binhist (LDS) -> 391-bin scan -> stage -> place2
//    (place2 derives per-node count/row_start/dinv from staged pairs in LDS).
//  - bf16 everywhere off the critical gather path is f32: GEMM computes f32,
//    outputs bf16 rows pre-scaled by dinv[row]; agg sums in f32, writes bf16
//    activations; layer-2/3 GEMMs stage bf16 A-tiles.
//  - EA/L3 traffic is the measured ceiling (~3.6 TB/s random) -> all changes
//    are byte reductions.

constexpr int HID = 128;
constexpr int BIN_SHIFT = 8;          // 256 dst nodes per bin
constexpr int MAXBINS = 512;          // nN <= 131072

static __device__ __forceinline__ void fma4(float4& a, float s, const float4& b) {
    a.x += s * b.x; a.y += s * b.y; a.z += s * b.z; a.w += s * b.w;
}
static __device__ __forceinline__ unsigned bf16rne(float f) {
    unsigned u = __float_as_uint(f);
    return (u + 0x7FFFu + ((u >> 16) & 1u)) >> 16;
}
static __device__ __forceinline__ unsigned packbf16(float lo, float hi) {
    return bf16rne(lo) | (bf16rne(hi) << 16);
}
static __device__ __forceinline__ float blo(unsigned u) { return __uint_as_float(u << 16); }
static __device__ __forceinline__ float bhi(unsigned u) { return __uint_as_float(u & 0xFFFF0000u); }

// ---------------- CSR build (binned) ----------------
__global__ __launch_bounds__(256) void k_binhist(const int* __restrict__ dst,
                                                 int* __restrict__ binc,
                                                 int nE, int nbins) {
    __shared__ int h[MAXBINS];
    const int tid = threadIdx.x;
    for (int t = tid; t < nbins; t += 256) h[t] = 0;
    __syncthreads();
    const long long e0 = (long long)blockIdx.x * 4096;
#pragma unroll
    for (int k = 0; k < 16; ++k) {
        long long e = e0 + k * 256 + tid;
        if (e < nE) atomicAdd(&h[dst[e] >> BIN_SHIFT], 1);
    }
    __syncthreads();
    for (int t = tid; t < nbins; t += 256)
        if (h[t]) atomicAdd(&binc[t], h[t]);
}

// single-WG exclusive scan over <=512 bins -> bin_start (+sentinel), bin_cursor
__global__ __launch_bounds__(512) void k_scanbins(const int* __restrict__ binc,
                                                  int* __restrict__ bin_start,
                                                  int* __restrict__ bin_cursor,
                                                  int nbins, int nE) {
    __shared__ int lds[512];
    const int tid = threadIdx.x;
    int v = (tid < nbins) ? binc[tid] : 0;
    lds[tid] = v;
    __syncthreads();
    for (int off = 1; off < 512; off <<= 1) {
        int u = (tid >= off) ? lds[tid - off] : 0;
        __syncthreads();
        lds[tid] += u;
        __syncthreads();
    }
    int excl = lds[tid] - v;
    if (tid < nbins) { bin_start[tid] = excl; bin_cursor[tid] = excl; }
    if (tid == 0) bin_start[nbins] = nE;
}

// Phase 1: bin (src,dst) pairs into dst-range bins; per-WG span reservation
// keeps staged writes line-dense.
__global__ __launch_bounds__(256) void k_stage(const int* __restrict__ src,
                                               const int* __restrict__ dst,
                                               int* __restrict__ bin_cursor,
                                               int2* __restrict__ staged,
                                               int nE, int nbins) {
    __shared__ int hist[MAXBINS];
    __shared__ int wbase[MAXBINS];
    __shared__ int rank[MAXBINS];
    const int tid = threadIdx.x;
    const long long e0 = (long long)blockIdx.x * 4096;
    int es[16], ed[16];
#pragma unroll
    for (int k = 0; k < 16; ++k) {
        long long e = e0 + k * 256 + tid;
        if (e < nE) { es[k] = src[e]; ed[k] = dst[e]; }
        else        { es[k] = 0; ed[k] = -1; }
    }
    for (int t = tid; t < nbins; t += 256) { hist[t] = 0; rank[t] = 0; }
    __syncthreads();
#pragma unroll
    for (int k = 0; k < 16; ++k)
        if (ed[k] >= 0) atomicAdd(&hist[ed[k] >> BIN_SHIFT], 1);
    __syncthreads();
    for (int t = tid; t < nbins; t += 256)
        wbase[t] = hist[t] ? atomicAdd(&bin_cursor[t], hist[t]) : 0;
    __syncthreads();
#pragma unroll
    for (int k = 0; k < 16; ++k)
        if (ed[k] >= 0) {
            int b = ed[k] >> BIN_SHIFT;
            int r = atomicAdd(&rank[b], 1);
            staged[wbase[b] + r] = make_int2(es[k], ed[k]);
        }
}

// Phase 2: one WG per bin. From the bin's staged pairs derive per-node counts
// (LDS), scan -> row_start + dinv, then place esrc via LDS cursors.
__global__ __launch_bounds__(256) void k_place2(const int* __restrict__ bin_start,
                                                const int2* __restrict__ staged,
                                                int* __restrict__ esrc,
                                                int* __restrict__ row_start,
                                                float* __restrict__ dinv, int nN) {
    __shared__ int cnt[1 << BIN_SHIFT];
    __shared__ int sc[1 << BIN_SHIFT];
    const int b = blockIdx.x;
    const int tid = threadIdx.x;
    const int d0 = b << BIN_SHIFT;
    const int dend = min(d0 + (1 << BIN_SHIFT), nN);
    const int p0 = bin_start[b];
    const int p1 = bin_start[b + 1];
    cnt[tid] = 0;
    __syncthreads();
    for (int i = p0 + tid; i < p1; i += 256)
        atomicAdd(&cnt[staged[i].y - d0], 1);
    __syncthreads();
    const int my = cnt[tid];
    sc[tid] = my;
    __syncthreads();
    for (int off = 1; off < 256; off <<= 1) {
        int v = (tid >= off) ? sc[tid - off] : 0;
        __syncthreads();
        sc[tid] += v;
        __syncthreads();
    }
    const int excl = sc[tid] - my;
    const int d = d0 + tid;
    if (d < dend) {
        row_start[d] = p0 + excl;
        dinv[d] = rsqrtf((float)my + 1.0f);   // +1 self-loop
    }
    if (tid == 0 && dend == nN) row_start[nN] = p1;
    __syncthreads();
    cnt[tid] = p0 + excl;   // reuse as cursor
    __syncthreads();
    for (int i = p0 + tid; i < p1; i += 256) {
        int2 pr = staged[i];
        int pos = atomicAdd(&cnt[pr.y - d0], 1);
        esrc[pos] = pr.x;
    }
}

// ---------------- GEMM (A f32) -> bf16 rows scaled by dinv[row] -----------
__global__ __launch_bounds__(256) void k_gemm3(const float* __restrict__ A,
                                               const float* __restrict__ W,
                                               const float* __restrict__ dinv,
                                               unsigned* __restrict__ h16, int n) {
    __shared__ float As[64][68];
    __shared__ float Ws[64][128];
    const int tid = threadIdx.x;
    const int tc = tid & 15;
    const int tr = tid >> 4;
    const int row0 = blockIdx.x * 64;

    float4 acc0[4] = {}, acc1[4] = {};

    for (int pass = 0; pass < 2; ++pass) {
        const int kb = pass * 64;
        for (int it = 0; it < 4; ++it) {
            int flat = it * 256 + tid;
            int r = flat >> 4, k4 = flat & 15;
            int gr = row0 + r;
            float4 v = make_float4(0.f, 0.f, 0.f, 0.f);
            if (gr < n) v = *(const float4*)(A + (size_t)gr * HID + kb + k4 * 4);
            *(float4*)(&As[r][k4 * 4]) = v;
        }
        for (int it = 0; it < 8; ++it) {
            int flat = it * 256 + tid;
            int k = flat >> 5, c4 = flat & 31;
            *(float4*)(&Ws[k][c4 * 4]) = *(const float4*)(W + (size_t)(kb + k) * HID + c4 * 4);
        }
        __syncthreads();

#pragma unroll 2
        for (int k4 = 0; k4 < 16; ++k4) {
            float ar[4][4];
            *(float4*)&ar[0][0] = *(const float4*)(&As[tr * 4 + 0][k4 * 4]);
            *(float4*)&ar[1][0] = *(const float4*)(&As[tr * 4 + 1][k4 * 4]);
            *(float4*)&ar[2][0] = *(const float4*)(&As[tr * 4 + 2][k4 * 4]);
            *(float4*)&ar[3][0] = *(const float4*)(&As[tr * 4 + 3][k4 * 4]);
#pragma unroll
            for (int j = 0; j < 4; ++j) {
                float4 b0 = *(const float4*)(&Ws[k4 * 4 + j][tc * 4]);
                float4 b1 = *(const float4*)(&Ws[k4 * 4 + j][64 + tc * 4]);
#pragma unroll
                for (int i = 0; i < 4; ++i) {
                    fma4(acc0[i], ar[i][j], b0);
                    fma4(acc1[i], ar[i][j], b1);
                }
            }
        }
        __syncthreads();
    }

#pragma unroll
    for (int i = 0; i < 4; ++i) {
        int r = row0 + tr * 4 + i;
        if (r < n) {
            float di = dinv[r];
            float4 a0 = acc0[i], a1 = acc1[i];
            uint2 p0, p1;
            p0.x = packbf16(a0.x * di, a0.y * di);
            p0.y = packbf16(a0.z * di, a0.w * di);
            p1.x = packbf16(a1.x * di, a1.y * di);
            p1.y = packbf16(a1.z * di, a1.w * di);
            *(uint2*)(h16 + (size_t)r * 64 + tc * 2) = p0;
            *(uint2*)(h16 + (size_t)r * 64 + 32 + tc * 2) = p1;
        }
    }
}

// ---------------- GEMM (A bf16) -> bf16 rows scaled by dinv[row] ----------
__global__ __launch_bounds__(256) void k_gemm3b(const unsigned* __restrict__ A16,
                                                const float* __restrict__ W,
                                                const float* __restrict__ dinv,
                                                unsigned* __restrict__ h16, int n) {
    __shared__ float As[64][68];
    __shared__ float Ws[64][128];
    const int tid = threadIdx.x;
    const int tc = tid & 15;
    const int tr = tid >> 4;
    const int row0 = blockIdx.x * 64;

    float4 acc0[4] = {}, acc1[4] = {};

    for (int pass = 0; pass < 2; ++pass) {
        const int kb = pass * 64;
        // stage A tile from bf16: 64 rows x 16 uint2 (=64 k) per pass
        for (int it = 0; it < 4; ++it) {
            int flat = it * 256 + tid;
            int r = flat >> 4, q = flat & 15;
            int gr = row0 + r;
            uint2 u = make_uint2(0u, 0u);
            if (gr < n) u = *(const uint2*)(A16 + (size_t)gr * 64 + kb / 2 + q * 2);
            float4 w = make_float4(blo(u.x), bhi(u.x), blo(u.y), bhi(u.y));
            *(float4*)(&As[r][q * 4]) = w;
        }
        for (int it = 0; it < 8; ++it) {
            int flat = it * 256 + tid;
            int k = flat >> 5, c4 = flat & 31;
            *(float4*)(&Ws[k][c4 * 4]) = *(const float4*)(W + (size_t)(kb + k) * HID + c4 * 4);
        }
        __syncthreads();

#pragma unroll 2
        for (int k4 = 0; k4 < 16; ++k4) {
            float ar[4][4];
            *(float4*)&ar[0][0] = *(const float4*)(&As[tr * 4 + 0][k4 * 4]);
            *(float4*)&ar[1][0] = *(const float4*)(&As[tr * 4 + 1][k4 * 4]);
            *(float4*)&ar[2][0] = *(const float4*)(&As[tr * 4 + 2][k4 * 4]);
            *(float4*)&ar[3][0] = *(const float4*)(&As[tr * 4 + 3][k4 * 4]);
#pragma unroll
            for (int j = 0; j < 4; ++j) {
                float4 b0 = *(const float4*)(&Ws[k4 * 4 + j][tc * 4]);
                float4 b1 = *(const float4*)(&Ws[k4 * 4 + j][64 + tc * 4]);
#pragma unroll
                for (int i = 0; i < 4; ++i) {
                    fma4(acc0[i], ar[i][j], b0);
                    fma4(acc1[i], ar[i][j], b1);
                }
            }
        }
        __syncthreads();
    }

#pragma unroll
    for (int i = 0; i < 4; ++i) {
        int r = row0 + tr * 4 + i;
        if (r < n) {
            float di = dinv[r];
            float4 a0 = acc0[i], a1 = acc1[i];
            uint2 p0, p1;
            p0.x = packbf16(a0.x * di, a0.y * di);
            p0.y = packbf16(a0.z * di, a0.w * di);
            p1.x = packbf16(a1.x * di, a1.y * di);
            p1.y = packbf16(a1.z * di, a1.w * di);
            *(uint2*)(h16 + (size_t)r * 64 + tc * 2) = p0;
            *(uint2*)(h16 + (size_t)r * 64 + 32 + tc * 2) = p1;
        }
    }
}

// ---------------- fused gather-aggregate + bias + ReLU --------------------
// One wave per dst node; lane owns 2 channels (one u32 = 2 bf16). Rows are
// pre-scaled by dinv[src]; out = relu(dd * (sum_nbr + self) + b).
// out16 != null: write bf16 activation. Else: atomically pool into sums.
__global__ __launch_bounds__(256) void k_agg16(const int* __restrict__ row_start,
                                               const int* __restrict__ esrc,
                                               const float* __restrict__ dinv,
                                               const unsigned* __restrict__ h16,
                                               const float* __restrict__ bias,
                                               unsigned* __restrict__ out16, int n,
                                               float* __restrict__ pool_sums,
                                               const int* __restrict__ batch) {
    int t = blockIdx.x * 256 + threadIdx.x;
    int node = t >> 6;
    if (node >= n) return;
    const int lane = t & 63;
    int e0 = row_start[node], e1 = row_start[node + 1];
    e0 = __builtin_amdgcn_readfirstlane(e0);
    e1 = __builtin_amdgcn_readfirstlane(e1);
    float dd = dinv[node];

    unsigned su = h16[(size_t)node * 64 + lane];   // self row (pre-scaled)
    float ax = blo(su), ay = bhi(su);

    int e = e0;
    for (; e + 4 <= e1; e += 4) {
        int s0 = __builtin_amdgcn_readfirstlane(esrc[e + 0]);
        int s1 = __builtin_amdgcn_readfirstlane(esrc[e + 1]);
        int s2 = __builtin_amdgcn_readfirstlane(esrc[e + 2]);
        int s3 = __builtin_amdgcn_readfirstlane(esrc[e + 3]);
        unsigned u0 = h16[(size_t)s0 * 64 + lane];
        unsigned u1 = h16[(size_t)s1 * 64 + lane];
        unsigned u2 = h16[(size_t)s2 * 64 + lane];
        unsigned u3 = h16[(size_t)s3 * 64 + lane];
        ax += blo(u0) + blo(u1) + blo(u2) + blo(u3);
        ay += bhi(u0) + bhi(u1) + bhi(u2) + bhi(u3);
    }
    for (; e < e1; ++e) {
        int s = __builtin_amdgcn_readfirstlane(esrc[e]);
        unsigned u = h16[(size_t)s * 64 + lane];
        ax += blo(u);
        ay += bhi(u);
    }

    const float2 bv = *(const float2*)(bias + 2 * lane);
    float ox = fmaxf(ax * dd + bv.x, 0.f);
    float oy = fmaxf(ay * dd + bv.y, 0.f);
    if (out16) {
        out16[(size_t)node * 64 + lane] = packbf16(ox, oy);
    } else {
        float* p = &pool_sums[(size_t)batch[node] * HID + 2 * lane];
        atomicAdd(p, ox);
        atomicAdd(p + 1, oy);
    }
}

// ---------------- pooling / head ----------------
__global__ __launch_bounds__(256) void k_count(const int* __restrict__ batch,
                                               float* __restrict__ cnt, int n) {
    int i = blockIdx.x * 256 + threadIdx.x;
    if (i < n) atomicAdd(&cnt[batch[i]], 1.0f);
}

__global__ __launch_bounds__(64) void k_mlp(const float* __restrict__ sums,
                                            const float* __restrict__ cnt,
                                            const float* __restrict__ lw1,
                                            const float* __restrict__ lb1,
                                            const float* __restrict__ lw2,
                                            const float* __restrict__ lb2,
                                            float* __restrict__ out) {
    int g = blockIdx.x;
    int j = threadIdx.x;
    float inv = 1.0f / fmaxf(cnt[g], 1.0f);
    const float* srow = sums + (size_t)g * HID;
    float acc = lb1[j];
#pragma unroll 8
    for (int k = 0; k < HID; ++k) acc += srow[k] * inv * lw1[k * 64 + j];
    acc = fmaxf(acc, 0.0f);
    float prod = acc * lw2[j];
#pragma unroll
    for (int off = 32; off > 0; off >>= 1) prod += __shfl_down(prod, off);
    if (j == 0) out[g] = prod + lb2[0];
}

extern "C" void kernel_launch(void* const* d_in, const int* in_sizes, int n_in,
                              void* d_out, int out_size, void* d_ws, size_t ws_size,
                              hipStream_t stream) {
    const float* x   = (const float*)d_in[0];
    const int*   ei  = (const int*)d_in[1];
    const int*   bat = (const int*)d_in[2];
    const float* W1  = (const float*)d_in[3];
    const float* b1  = (const float*)d_in[4];
    const float* W2  = (const float*)d_in[5];
    const float* b2  = (const float*)d_in[6];
    const float* W3  = (const float*)d_in[7];
    const float* b3  = (const float*)d_in[8];
    const float* lw1 = (const float*)d_in[9];
    const float* lb1 = (const float*)d_in[10];
    const float* lw2 = (const float*)d_in[11];
    const float* lb2 = (const float*)d_in[12];
    float* out = (float*)d_out;

    const int nN = in_sizes[2];       // 100000
    const int nE = in_sizes[1] / 2;   // 3200000
    const int G  = out_size;          // 4096
    const int* src = ei;
    const int* dst = ei + nE;

    const int nbins = (nN + (1 << BIN_SHIFT) - 1) >> BIN_SHIFT;  // 391 (<=512)

    // workspace layout
    char* p = (char*)d_ws;
    auto alloc = [&](size_t bytes) { char* r = p; p += (bytes + 255) & ~(size_t)255; return r; };
    unsigned* act16     = (unsigned*)alloc(sizeof(unsigned) * (size_t)nN * 64);
    unsigned* h16       = (unsigned*)alloc(sizeof(unsigned) * (size_t)nN * 64);  // also staged (int2 nE == same bytes)
    float*    dinv      = (float*)alloc(sizeof(float) * nN);
    float*    sums      = (float*)alloc(sizeof(float) * (size_t)G * HID);
    float*    cnt       = (float*)alloc(sizeof(float) * G);
    int*      binc      = (int*)alloc(sizeof(int) * (nbins + 1));
    int*      bin_start = (int*)alloc(sizeof(int) * (nbins + 1));
    int*      bin_cur   = (int*)alloc(sizeof(int) * (nbins + 1));
    int*      row_start = (int*)alloc(sizeof(int) * (nN + 1));
    int*      esrc      = (int*)alloc(sizeof(int) * (size_t)nE);
    int2*     staged    = (int2*)h16;  // consumed by k_place2 before gemm writes h16

    const int gemmGrid = (nN + 63) / 64;
    const int aggGrid  = (int)(((long long)nN * 64 + 255) / 256);
    const int edgeWGs  = (int)(((long long)nE + 4095) / 4096);

    // ---- CSR build (binned) ----
    hipMemsetAsync(binc, 0, sizeof(int) * nbins, stream);
    k_binhist<<<edgeWGs, 256, 0, stream>>>(dst, binc, nE, nbins);
    k_scanbins<<<1, 512, 0, stream>>>(binc, bin_start, bin_cur, nbins, nE);
    k_stage<<<edgeWGs, 256, 0, stream>>>(src, dst, bin_cur, staged, nE, nbins);
    k_place2<<<nbins, 256, 0, stream>>>(bin_start, staged, esrc, row_start, dinv, nN);

    // ---- pooling denominators ----
    hipMemsetAsync(sums, 0, sizeof(float) * ((size_t)G * HID + G), stream);
    k_count<<<(nN + 255) / 256, 256, 0, stream>>>(bat, cnt, nN);

    // ---- 3 GCN layers ----
    k_gemm3 <<<gemmGrid, 256, 0, stream>>>(x, W1, dinv, h16, nN);
    k_agg16 <<<aggGrid, 256, 0, stream>>>(row_start, esrc, dinv, h16, b1, act16, nN, nullptr, nullptr);
    k_gemm3b<<<gemmGrid, 256, 0, stream>>>(act16, W2, dinv, h16, nN);
    k_agg16 <<<aggGrid, 256, 0, stream>>>(row_start, esrc, dinv, h16, b2, act16, nN, nullptr, nullptr);
    k_gemm3b<<<gemmGrid, 256, 0, stream>>>(act16, W3, dinv, h16, nN);
    k_agg16 <<<aggGrid, 256, 0, stream>>>(row_start, esrc, dinv, h16, b3, nullptr, nN, sums, bat);

    // ---- head ----
    k_mlp<<<G, 64, 0, stream>>>(sums, cnt, lw1, lb1, lw2, lb2, out);
}

// Round 10
// 533.047 us; speedup vs baseline: 2.0801x; 1.1928x over previous
//
#include <hip/hip_runtime.h>

// GCN regressor, round 10:
//  - GEMMs on matrix cores: mfma_f32_16x16x32_bf16, W quantized to bf16 and
//    transposed into LDS per block; bf16 output rows pre-scaled by dinv.
//  - CSR build fully binned (binhist -> 391-bin scan -> stage -> place2).
//  - agg16: f32-sum gather over bf16 rows (unchanged; pinned at ~3.6 TB/s
//    random-fabric ceiling, 368 MB FETCH per layer).

constexpr int HID = 128;
constexpr int BIN_SHIFT = 8;          // 256 dst nodes per bin
constexpr int MAXBINS = 512;          // nN <= 131072

typedef float f32x4 __attribute__((ext_vector_type(4)));
typedef short short8 __attribute__((ext_vector_type(8)));

static __device__ __forceinline__ unsigned bf16rne(float f) {
    unsigned u = __float_as_uint(f);
    return (u + 0x7FFFu + ((u >> 16) & 1u)) >> 16;
}
static __device__ __forceinline__ unsigned packbf16(float lo, float hi) {
    return bf16rne(lo) | (bf16rne(hi) << 16);
}
static __device__ __forceinline__ float blo(unsigned u) { return __uint_as_float(u << 16); }
static __device__ __forceinline__ float bhi(unsigned u) { return __uint_as_float(u & 0xFFFF0000u); }

// ---------------- CSR build (binned) ----------------
__global__ __launch_bounds__(256) void k_binhist(const int* __restrict__ dst,
                                                 int* __restrict__ binc,
                                                 int nE, int nbins) {
    __shared__ int h[MAXBINS];
    const int tid = threadIdx.x;
    for (int t = tid; t < nbins; t += 256) h[t] = 0;
    __syncthreads();
    const long long e0 = (long long)blockIdx.x * 4096;
#pragma unroll
    for (int k = 0; k < 16; ++k) {
        long long e = e0 + k * 256 + tid;
        if (e < nE) atomicAdd(&h[dst[e] >> BIN_SHIFT], 1);
    }
    __syncthreads();
    for (int t = tid; t < nbins; t += 256)
        if (h[t]) atomicAdd(&binc[t], h[t]);
}

__global__ __launch_bounds__(512) void k_scanbins(const int* __restrict__ binc,
                                                  int* __restrict__ bin_start,
                                                  int* __restrict__ bin_cursor,
                                                  int nbins, int nE) {
    __shared__ int lds[512];
    const int tid = threadIdx.x;
    int v = (tid < nbins) ? binc[tid] : 0;
    lds[tid] = v;
    __syncthreads();
    for (int off = 1; off < 512; off <<= 1) {
        int u = (tid >= off) ? lds[tid - off] : 0;
        __syncthreads();
        lds[tid] += u;
        __syncthreads();
    }
    int excl = lds[tid] - v;
    if (tid < nbins) { bin_start[tid] = excl; bin_cursor[tid] = excl; }
    if (tid == 0) bin_start[nbins] = nE;
}

__global__ __launch_bounds__(256) void k_stage(const int* __restrict__ src,
                                               const int* __restrict__ dst,
                                               int* __restrict__ bin_cursor,
                                               int2* __restrict__ staged,
                                               int nE, int nbins) {
    __shared__ int hist[MAXBINS];
    __shared__ int wbase[MAXBINS];
    __shared__ int rank[MAXBINS];
    const int tid = threadIdx.x;
    const long long e0 = (long long)blockIdx.x * 4096;
    int es[16], ed[16];
#pragma unroll
    for (int k = 0; k < 16; ++k) {
        long long e = e0 + k * 256 + tid;
        if (e < nE) { es[k] = src[e]; ed[k] = dst[e]; }
        else        { es[k] = 0; ed[k] = -1; }
    }
    for (int t = tid; t < nbins; t += 256) { hist[t] = 0; rank[t] = 0; }
    __syncthreads();
#pragma unroll
    for (int k = 0; k < 16; ++k)
        if (ed[k] >= 0) atomicAdd(&hist[ed[k] >> BIN_SHIFT], 1);
    __syncthreads();
    for (int t = tid; t < nbins; t += 256)
        wbase[t] = hist[t] ? atomicAdd(&bin_cursor[t], hist[t]) : 0;
    __syncthreads();
#pragma unroll
    for (int k = 0; k < 16; ++k)
        if (ed[k] >= 0) {
            int b = ed[k] >> BIN_SHIFT;
            int r = atomicAdd(&rank[b], 1);
            staged[wbase[b] + r] = make_int2(es[k], ed[k]);
        }
}

__global__ __launch_bounds__(256) void k_place2(const int* __restrict__ bin_start,
                                                const int2* __restrict__ staged,
                                                int* __restrict__ esrc,
                                                int* __restrict__ row_start,
                                                float* __restrict__ dinv, int nN) {
    __shared__ int cnt[1 << BIN_SHIFT];
    __shared__ int sc[1 << BIN_SHIFT];
    const int b = blockIdx.x;
    const int tid = threadIdx.x;
    const int d0 = b << BIN_SHIFT;
    const int dend = min(d0 + (1 << BIN_SHIFT), nN);
    const int p0 = bin_start[b];
    const int p1 = bin_start[b + 1];
    cnt[tid] = 0;
    __syncthreads();
    for (int i = p0 + tid; i < p1; i += 256)
        atomicAdd(&cnt[staged[i].y - d0], 1);
    __syncthreads();
    const int my = cnt[tid];
    sc[tid] = my;
    __syncthreads();
    for (int off = 1; off < 256; off <<= 1) {
        int v = (tid >= off) ? sc[tid - off] : 0;
        __syncthreads();
        sc[tid] += v;
        __syncthreads();
    }
    const int excl = sc[tid] - my;
    const int d = d0 + tid;
    if (d < dend) {
        row_start[d] = p0 + excl;
        dinv[d] = rsqrtf((float)my + 1.0f);   // +1 self-loop
    }
    if (tid == 0 && dend == nN) row_start[nN] = p1;
    __syncthreads();
    cnt[tid] = p0 + excl;   // reuse as cursor
    __syncthreads();
    for (int i = p0 + tid; i < p1; i += 256) {
        int2 pr = staged[i];
        int pos = atomicAdd(&cnt[pr.y - d0], 1);
        esrc[pos] = pr.x;
    }
}

// ---------------- MFMA GEMM: h16[r] = bf16( (A[r,:]@W) * dinv[r] ) --------
// 64 rows/block, 4 waves x (16 rows x 128 cols). W -> bf16 transposed in LDS.
// A_F32: A is f32 [n][128] (layer 1); else packed bf16 u32 [n][64].
template <bool A_F32>
__global__ __launch_bounds__(256) void k_gemm_mfma(const void* __restrict__ Aptr,
                                                   const float* __restrict__ W,
                                                   const float* __restrict__ dinv,
                                                   unsigned* __restrict__ h16, int n) {
    __shared__ unsigned lds[128 * 68];   // Wt bf16 [col][k2] stride 68; reused as C-bounce
    const int tid  = threadIdx.x;
    const int lane = tid & 63;
    const int w    = tid >> 6;           // wave 0..3
    const int colb = lane & 15;
    const int kg   = lane >> 4;          // 0..3
    const int row0 = blockIdx.x * 64;

    // stage Wt = bf16(W)^T : lds[c*68 + k2] = pack(W[2k2][c], W[2k2+1][c])
    for (int it = 0; it < 32; ++it) {
        int f = it * 256 + tid;
        int c = f & 127, k2 = f >> 7;
        float w0 = W[(size_t)(2 * k2) * HID + c];
        float w1 = W[(size_t)(2 * k2 + 1) * HID + c];
        lds[c * 68 + k2] = packbf16(w0, w1);
    }

    // A fragments: lane holds A[r][kc*32 + kg*8 + 0..7] as 8 bf16 (uint4)
    const int r = row0 + w * 16 + colb;
    uint4 a[4] = {};
    if (r < n) {
        if constexpr (A_F32) {
            const float* A = (const float*)Aptr;
#pragma unroll
            for (int kc = 0; kc < 4; ++kc) {
                const float* p = A + (size_t)r * HID + kc * 32 + kg * 8;
                float4 f0 = *(const float4*)(p);
                float4 f1 = *(const float4*)(p + 4);
                a[kc].x = packbf16(f0.x, f0.y);
                a[kc].y = packbf16(f0.z, f0.w);
                a[kc].z = packbf16(f1.x, f1.y);
                a[kc].w = packbf16(f1.z, f1.w);
            }
        } else {
            const unsigned* A16 = (const unsigned*)Aptr;
#pragma unroll
            for (int kc = 0; kc < 4; ++kc)
                a[kc] = *(const uint4*)(A16 + (size_t)r * 64 + kc * 16 + kg * 4);
        }
    }
    __syncthreads();

    // MFMA: acc[ct] += A(16x32) x Wt-tile(32x16)
    f32x4 acc[8] = {};
#pragma unroll
    for (int ct = 0; ct < 8; ++ct) {
#pragma unroll
        for (int kc = 0; kc < 4; ++kc) {
            uint4 bu = *(const uint4*)&lds[(ct * 16 + colb) * 68 + kc * 16 + kg * 4];
            acc[ct] = __builtin_amdgcn_mfma_f32_16x16x32_bf16(
                __builtin_bit_cast(short8, a[kc]),
                __builtin_bit_cast(short8, bu),
                acc[ct], 0, 0, 0);
        }
    }

    // epilogue: bounce via LDS (overlay), scale by dinv, pack bf16, store
    __syncthreads();
    float* Cb = (float*)lds;             // [64][132]
#pragma unroll
    for (int ct = 0; ct < 8; ++ct)
#pragma unroll
        for (int reg = 0; reg < 4; ++reg)
            Cb[(w * 16 + kg * 4 + reg) * 132 + ct * 16 + colb] = acc[ct][reg];
    __syncthreads();
    for (int it = 0; it < 16; ++it) {
        int f = it * 256 + tid;
        int rl = f >> 6, cw = f & 63;
        int gr = row0 + rl;
        if (gr < n) {
            float di = dinv[gr];
            float2 v = *(const float2*)&Cb[rl * 132 + 2 * cw];
            h16[(size_t)gr * 64 + cw] = packbf16(v.x * di, v.y * di);
        }
    }
}

// ---------------- fused gather-aggregate + bias + ReLU --------------------
// One wave per dst node; lane owns 2 channels (one u32 = 2 bf16). Rows are
// pre-scaled by dinv[src]; out = relu(dd * (sum_nbr + self) + b).
__global__ __launch_bounds__(256) void k_agg16(const int* __restrict__ row_start,
                                               const int* __restrict__ esrc,
                                               const float* __restrict__ dinv,
                                               const unsigned* __restrict__ h16,
                                               const float* __restrict__ bias,
                                               unsigned* __restrict__ out16, int n,
                                               float* __restrict__ pool_sums,
                                               const int* __restrict__ batch) {
    int t = blockIdx.x * 256 + threadIdx.x;
    int node = t >> 6;
    if (node >= n) return;
    const int lane = t & 63;
    int e0 = row_start[node], e1 = row_start[node + 1];
    e0 = __builtin_amdgcn_readfirstlane(e0);
    e1 = __builtin_amdgcn_readfirstlane(e1);
    float dd = dinv[node];

    unsigned su = h16[(size_t)node * 64 + lane];   // self row (pre-scaled)
    float ax = blo(su), ay = bhi(su);

    int e = e0;
    for (; e + 4 <= e1; e += 4) {
        int s0 = __builtin_amdgcn_readfirstlane(esrc[e + 0]);
        int s1 = __builtin_amdgcn_readfirstlane(esrc[e + 1]);
        int s2 = __builtin_amdgcn_readfirstlane(esrc[e + 2]);
        int s3 = __builtin_amdgcn_readfirstlane(esrc[e + 3]);
        unsigned u0 = h16[(size_t)s0 * 64 + lane];
        unsigned u1 = h16[(size_t)s1 * 64 + lane];
        unsigned u2 = h16[(size_t)s2 * 64 + lane];
        unsigned u3 = h16[(size_t)s3 * 64 + lane];
        ax += blo(u0) + blo(u1) + blo(u2) + blo(u3);
        ay += bhi(u0) + bhi(u1) + bhi(u2) + bhi(u3);
    }
    for (; e < e1; ++e) {
        int s = __builtin_amdgcn_readfirstlane(esrc[e]);
        unsigned u = h16[(size_t)s * 64 + lane];
        ax += blo(u);
        ay += bhi(u);
    }

    const float2 bv = *(const float2*)(bias + 2 * lane);
    float ox = fmaxf(ax * dd + bv.x, 0.f);
    float oy = fmaxf(ay * dd + bv.y, 0.f);
    if (out16) {
        out16[(size_t)node * 64 + lane] = packbf16(ox, oy);
    } else {
        float* p = &pool_sums[(size_t)batch[node] * HID + 2 * lane];
        atomicAdd(p, ox);
        atomicAdd(p + 1, oy);
    }
}

// ---------------- pooling / head ----------------
__global__ __launch_bounds__(256) void k_count(const int* __restrict__ batch,
                                               float* __restrict__ cnt, int n) {
    int i = blockIdx.x * 256 + threadIdx.x;
    if (i < n) atomicAdd(&cnt[batch[i]], 1.0f);
}

__global__ __launch_bounds__(64) void k_mlp(const float* __restrict__ sums,
                                            const float* __restrict__ cnt,
                                            const float* __restrict__ lw1,
                                            const float* __restrict__ lb1,
                                            const float* __restrict__ lw2,
                                            const float* __restrict__ lb2,
                                            float* __restrict__ out) {
    int g = blockIdx.x;
    int j = threadIdx.x;
    float inv = 1.0f / fmaxf(cnt[g], 1.0f);
    const float* srow = sums + (size_t)g * HID;
    float acc = lb1[j];
#pragma unroll 8
    for (int k = 0; k < HID; ++k) acc += srow[k] * inv * lw1[k * 64 + j];
    acc = fmaxf(acc, 0.0f);
    float prod = acc * lw2[j];
#pragma unroll
    for (int off = 32; off > 0; off >>= 1) prod += __shfl_down(prod, off);
    if (j == 0) out[g] = prod + lb2[0];
}

extern "C" void kernel_launch(void* const* d_in, const int* in_sizes, int n_in,
                              void* d_out, int out_size, void* d_ws, size_t ws_size,
                              hipStream_t stream) {
    const float* x   = (const float*)d_in[0];
    const int*   ei  = (const int*)d_in[1];
    const int*   bat = (const int*)d_in[2];
    const float* W1  = (const float*)d_in[3];
    const float* b1  = (const float*)d_in[4];
    const float* W2  = (const float*)d_in[5];
    const float* b2  = (const float*)d_in[6];
    const float* W3  = (const float*)d_in[7];
    const float* b3  = (const float*)d_in[8];
    const float* lw1 = (const float*)d_in[9];
    const float* lb1 = (const float*)d_in[10];
    const float* lw2 = (const float*)d_in[11];
    const float* lb2 = (const float*)d_in[12];
    float* out = (float*)d_out;

    const int nN = in_sizes[2];       // 100000
    const int nE = in_sizes[1] / 2;   // 3200000
    const int G  = out_size;          // 4096
    const int* src = ei;
    const int* dst = ei + nE;

    const int nbins = (nN + (1 << BIN_SHIFT) - 1) >> BIN_SHIFT;  // 391 (<=512)

    // workspace layout
    char* p = (char*)d_ws;
    auto alloc = [&](size_t bytes) { char* r = p; p += (bytes + 255) & ~(size_t)255; return r; };
    unsigned* act16     = (unsigned*)alloc(sizeof(unsigned) * (size_t)nN * 64);
    unsigned* h16       = (unsigned*)alloc(sizeof(unsigned) * (size_t)nN * 64);  // also staged (int2 nE)
    float*    dinv      = (float*)alloc(sizeof(float) * nN);
    float*    sums      = (float*)alloc(sizeof(float) * (size_t)G * HID);
    float*    cnt       = (float*)alloc(sizeof(float) * G);
    int*      binc      = (int*)alloc(sizeof(int) * (nbins + 1));
    int*      bin_start = (int*)alloc(sizeof(int) * (nbins + 1));
    int*      bin_cur   = (int*)alloc(sizeof(int) * (nbins + 1));
    int*      row_start = (int*)alloc(sizeof(int) * (nN + 1));
    int*      esrc      = (int*)alloc(sizeof(int) * (size_t)nE);
    int2*     staged    = (int2*)h16;  // consumed by k_place2 before gemm writes h16

    const int gemmGrid = (nN + 63) / 64;
    const int aggGrid  = (int)(((long long)nN * 64 + 255) / 256);
    const int edgeWGs  = (int)(((long long)nE + 4095) / 4096);

    // ---- CSR build (binned) ----
    hipMemsetAsync(binc, 0, sizeof(int) * nbins, stream);
    k_binhist<<<edgeWGs, 256, 0, stream>>>(dst, binc, nE, nbins);
    k_scanbins<<<1, 512, 0, stream>>>(binc, bin_start, bin_cur, nbins, nE);
    k_stage<<<edgeWGs, 256, 0, stream>>>(src, dst, bin_cur, staged, nE, nbins);
    k_place2<<<nbins, 256, 0, stream>>>(bin_start, staged, esrc, row_start, dinv, nN);

    // ---- pooling denominators ----
    hipMemsetAsync(sums, 0, sizeof(float) * ((size_t)G * HID + G), stream);
    k_count<<<(nN + 255) / 256, 256, 0, stream>>>(bat, cnt, nN);

    // ---- 3 GCN layers (MFMA GEMM + gather-agg) ----
    k_gemm_mfma<true ><<<gemmGrid, 256, 0, stream>>>(x, W1, dinv, h16, nN);
    k_agg16<<<aggGrid, 256, 0, stream>>>(row_start, esrc, dinv, h16, b1, act16, nN, nullptr, nullptr);
    k_gemm_mfma<false><<<gemmGrid, 256, 0, stream>>>(act16, W2, dinv, h16, nN);
    k_agg16<<<aggGrid, 256, 0, stream>>>(row_start, esrc, dinv, h16, b2, act16, nN, nullptr, nullptr);
    k_gemm_mfma<false><<<gemmGrid, 256, 0, stream>>>(act16, W3, dinv, h16, nN);
    k_agg16<<<aggGrid, 256, 0, stream>>>(row_start, esrc, dinv, h16, b3, nullptr, nN, sums, bat);

    // ---- head ----
    k_mlp<<<G, 64, 0, stream>>>(sums, cnt, lw1, lb1, lw2, lb2, out);
}

// Round 11
// 513.388 us; speedup vs baseline: 2.1598x; 1.0383x over previous
//
#include <hip/hip_runtime.h>

// GCN regressor, round 11:
//  - CSR build streamlined: fixed-capacity bins (16K/bin) kill binhist+scan;
//    staged packed to u32 (dstlocal<<24|src); place2 emits row_start+row_end.
//  - GEMMs on mfma_f32_16x16x32_bf16 (W->bf16^T in LDS, dinv-scaled bf16 out).
//  - agg16: f32-sum gather over bf16 rows; pinned at ~3.67 TB/s random-fabric
//    ceiling (368 MB L2-miss fetch per layer) -- structural for random graph.

constexpr int HID = 128;
constexpr int BIN_SHIFT = 8;          // 256 dst nodes per bin
constexpr int MAXBINS = 512;          // nN <= 131072
constexpr int CAP_SHIFT = 14;         // 16384 staged slots per bin (~2x mean)

typedef float f32x4 __attribute__((ext_vector_type(4)));
typedef short short8 __attribute__((ext_vector_type(8)));

static __device__ __forceinline__ unsigned bf16rne(float f) {
    unsigned u = __float_as_uint(f);
    return (u + 0x7FFFu + ((u >> 16) & 1u)) >> 16;
}
static __device__ __forceinline__ unsigned packbf16(float lo, float hi) {
    return bf16rne(lo) | (bf16rne(hi) << 16);
}
static __device__ __forceinline__ float blo(unsigned u) { return __uint_as_float(u << 16); }
static __device__ __forceinline__ float bhi(unsigned u) { return __uint_as_float(u & 0xFFFF0000u); }

// ---------------- CSR build (fixed-capacity bins) ----------------
__global__ __launch_bounds__(256) void k_initcur(int* __restrict__ bin_cur, int nbins) {
    int b = blockIdx.x * 256 + threadIdx.x;
    if (b < nbins) bin_cur[b] = b << CAP_SHIFT;
}

// Bin (src,dst) pairs into dst-range capacity regions; per-WG span
// reservation keeps staged writes line-dense. staged u32 = dstlocal<<24 | src.
__global__ __launch_bounds__(256) void k_stage(const int* __restrict__ src,
                                               const int* __restrict__ dst,
                                               int* __restrict__ bin_cursor,
                                               unsigned* __restrict__ staged,
                                               int nE, int nbins) {
    __shared__ int hist[MAXBINS];
    __shared__ int wbase[MAXBINS];
    __shared__ int rank[MAXBINS];
    const int tid = threadIdx.x;
    const long long e0 = (long long)blockIdx.x * 4096;
    int es[16], ed[16];
#pragma unroll
    for (int k = 0; k < 16; ++k) {
        long long e = e0 + k * 256 + tid;
        if (e < nE) { es[k] = src[e]; ed[k] = dst[e]; }
        else        { es[k] = 0; ed[k] = -1; }
    }
    for (int t = tid; t < nbins; t += 256) { hist[t] = 0; rank[t] = 0; }
    __syncthreads();
#pragma unroll
    for (int k = 0; k < 16; ++k)
        if (ed[k] >= 0) atomicAdd(&hist[ed[k] >> BIN_SHIFT], 1);
    __syncthreads();
    for (int t = tid; t < nbins; t += 256)
        wbase[t] = hist[t] ? atomicAdd(&bin_cursor[t], hist[t]) : 0;
    __syncthreads();
#pragma unroll
    for (int k = 0; k < 16; ++k)
        if (ed[k] >= 0) {
            int b = ed[k] >> BIN_SHIFT;
            int r = atomicAdd(&rank[b], 1);
            int w = wbase[b] + r;
            if (w < ((b + 1) << CAP_SHIFT))   // overflow guard (never hit at 90 sigma)
                staged[w] = ((unsigned)(ed[k] & ((1 << BIN_SHIFT) - 1)) << 24) | (unsigned)es[k];
        }
}

// One WG per bin: derive per-node counts from staged (LDS), scan ->
// row_start/row_end/dinv, then place esrc within the bin's capacity region.
__global__ __launch_bounds__(256) void k_place2(const int* __restrict__ bin_cur,
                                                const unsigned* __restrict__ staged,
                                                int* __restrict__ esrc,
                                                int* __restrict__ row_start,
                                                int* __restrict__ row_end,
                                                float* __restrict__ dinv, int nN) {
    __shared__ int cnt[1 << BIN_SHIFT];
    __shared__ int sc[1 << BIN_SHIFT];
    const int b = blockIdx.x;
    const int tid = threadIdx.x;
    const int d0 = b << BIN_SHIFT;
    const int dend = min(d0 + (1 << BIN_SHIFT), nN);
    const int p0 = b << CAP_SHIFT;
    const int p1 = bin_cur[b];
    cnt[tid] = 0;
    __syncthreads();
    for (int i = p0 + tid; i < p1; i += 256)
        atomicAdd(&cnt[staged[i] >> 24], 1);
    __syncthreads();
    const int my = cnt[tid];
    sc[tid] = my;
    __syncthreads();
    for (int off = 1; off < 256; off <<= 1) {
        int v = (tid >= off) ? sc[tid - off] : 0;
        __syncthreads();
        sc[tid] += v;
        __syncthreads();
    }
    const int excl = sc[tid] - my;
    const int d = d0 + tid;
    if (d < dend) {
        row_start[d] = p0 + excl;
        row_end[d]   = p0 + excl + my;
        dinv[d] = rsqrtf((float)my + 1.0f);   // +1 self-loop
    }
    __syncthreads();
    cnt[tid] = p0 + excl;   // reuse as cursor
    __syncthreads();
    for (int i = p0 + tid; i < p1; i += 256) {
        unsigned pr = staged[i];
        int pos = atomicAdd(&cnt[pr >> 24], 1);
        esrc[pos] = (int)(pr & 0xFFFFFFu);
    }
}

// ---------------- MFMA GEMM: h16[r] = bf16( (A[r,:]@W) * dinv[r] ) --------
// 64 rows/block, 4 waves x (16 rows x 128 cols). W -> bf16 transposed in LDS.
template <bool A_F32>
__global__ __launch_bounds__(256) void k_gemm_mfma(const void* __restrict__ Aptr,
                                                   const float* __restrict__ W,
                                                   const float* __restrict__ dinv,
                                                   unsigned* __restrict__ h16, int n) {
    __shared__ unsigned lds[128 * 68];   // Wt bf16 [col][k2] stride 68; reused as C-bounce
    const int tid  = threadIdx.x;
    const int lane = tid & 63;
    const int w    = tid >> 6;
    const int colb = lane & 15;
    const int kg   = lane >> 4;
    const int row0 = blockIdx.x * 64;

    for (int it = 0; it < 32; ++it) {
        int f = it * 256 + tid;
        int c = f & 127, k2 = f >> 7;
        float w0 = W[(size_t)(2 * k2) * HID + c];
        float w1 = W[(size_t)(2 * k2 + 1) * HID + c];
        lds[c * 68 + k2] = packbf16(w0, w1);
    }

    const int r = row0 + w * 16 + colb;
    uint4 a[4] = {};
    if (r < n) {
        if constexpr (A_F32) {
            const float* A = (const float*)Aptr;
#pragma unroll
            for (int kc = 0; kc < 4; ++kc) {
                const float* p = A + (size_t)r * HID + kc * 32 + kg * 8;
                float4 f0 = *(const float4*)(p);
                float4 f1 = *(const float4*)(p + 4);
                a[kc].x = packbf16(f0.x, f0.y);
                a[kc].y = packbf16(f0.z, f0.w);
                a[kc].z = packbf16(f1.x, f1.y);
                a[kc].w = packbf16(f1.z, f1.w);
            }
        } else {
            const unsigned* A16 = (const unsigned*)Aptr;
#pragma unroll
            for (int kc = 0; kc < 4; ++kc)
                a[kc] = *(const uint4*)(A16 + (size_t)r * 64 + kc * 16 + kg * 4);
        }
    }
    __syncthreads();

    f32x4 acc[8] = {};
#pragma unroll
    for (int ct = 0; ct < 8; ++ct) {
#pragma unroll
        for (int kc = 0; kc < 4; ++kc) {
            uint4 bu = *(const uint4*)&lds[(ct * 16 + colb) * 68 + kc * 16 + kg * 4];
            acc[ct] = __builtin_amdgcn_mfma_f32_16x16x32_bf16(
                __builtin_bit_cast(short8, a[kc]),
                __builtin_bit_cast(short8, bu),
                acc[ct], 0, 0, 0);
        }
    }

    __syncthreads();
    float* Cb = (float*)lds;             // [64][132]
#pragma unroll
    for (int ct = 0; ct < 8; ++ct)
#pragma unroll
        for (int reg = 0; reg < 4; ++reg)
            Cb[(w * 16 + kg * 4 + reg) * 132 + ct * 16 + colb] = acc[ct][reg];
    __syncthreads();
    for (int it = 0; it < 16; ++it) {
        int f = it * 256 + tid;
        int rl = f >> 6, cw = f & 63;
        int gr = row0 + rl;
        if (gr < n) {
            float di = dinv[gr];
            float2 v = *(const float2*)&Cb[rl * 132 + 2 * cw];
            h16[(size_t)gr * 64 + cw] = packbf16(v.x * di, v.y * di);
        }
    }
}

// ---------------- fused gather-aggregate + bias + ReLU --------------------
__global__ __launch_bounds__(256) void k_agg16(const int* __restrict__ row_start,
                                               const int* __restrict__ row_end,
                                               const int* __restrict__ esrc,
                                               const float* __restrict__ dinv,
                                               const unsigned* __restrict__ h16,
                                               const float* __restrict__ bias,
                                               unsigned* __restrict__ out16, int n,
                                               float* __restrict__ pool_sums,
                                               const int* __restrict__ batch) {
    int t = blockIdx.x * 256 + threadIdx.x;
    int node = t >> 6;
    if (node >= n) return;
    const int lane = t & 63;
    int e0 = row_start[node], e1 = row_end[node];
    e0 = __builtin_amdgcn_readfirstlane(e0);
    e1 = __builtin_amdgcn_readfirstlane(e1);
    float dd = dinv[node];

    unsigned su = h16[(size_t)node * 64 + lane];   // self row (pre-scaled)
    float ax = blo(su), ay = bhi(su);

    int e = e0;
    for (; e + 4 <= e1; e += 4) {
        int s0 = __builtin_amdgcn_readfirstlane(esrc[e + 0]);
        int s1 = __builtin_amdgcn_readfirstlane(esrc[e + 1]);
        int s2 = __builtin_amdgcn_readfirstlane(esrc[e + 2]);
        int s3 = __builtin_amdgcn_readfirstlane(esrc[e + 3]);
        unsigned u0 = h16[(size_t)s0 * 64 + lane];
        unsigned u1 = h16[(size_t)s1 * 64 + lane];
        unsigned u2 = h16[(size_t)s2 * 64 + lane];
        unsigned u3 = h16[(size_t)s3 * 64 + lane];
        ax += blo(u0) + blo(u1) + blo(u2) + blo(u3);
        ay += bhi(u0) + bhi(u1) + bhi(u2) + bhi(u3);
    }
    for (; e < e1; ++e) {
        int s = __builtin_amdgcn_readfirstlane(esrc[e]);
        unsigned u = h16[(size_t)s * 64 + lane];
        ax += blo(u);
        ay += bhi(u);
    }

    const float2 bv = *(const float2*)(bias + 2 * lane);
    float ox = fmaxf(ax * dd + bv.x, 0.f);
    float oy = fmaxf(ay * dd + bv.y, 0.f);
    if (out16) {
        out16[(size_t)node * 64 + lane] = packbf16(ox, oy);
    } else {
        float* p = &pool_sums[(size_t)batch[node] * HID + 2 * lane];
        atomicAdd(p, ox);
        atomicAdd(p + 1, oy);
    }
}

// ---------------- pooling / head ----------------
__global__ __launch_bounds__(256) void k_count(const int* __restrict__ batch,
                                               float* __restrict__ cnt, int n) {
    int i = blockIdx.x * 256 + threadIdx.x;
    if (i < n) atomicAdd(&cnt[batch[i]], 1.0f);
}

__global__ __launch_bounds__(64) void k_mlp(const float* __restrict__ sums,
                                            const float* __restrict__ cnt,
                                            const float* __restrict__ lw1,
                                            const float* __restrict__ lb1,
                                            const float* __restrict__ lw2,
                                            const float* __restrict__ lb2,
                                            float* __restrict__ out) {
    int g = blockIdx.x;
    int j = threadIdx.x;
    float inv = 1.0f / fmaxf(cnt[g], 1.0f);
    const float* srow = sums + (size_t)g * HID;
    float acc = lb1[j];
#pragma unroll 8
    for (int k = 0; k < HID; ++k) acc += srow[k] * inv * lw1[k * 64 + j];
    acc = fmaxf(acc, 0.0f);
    float prod = acc * lw2[j];
#pragma unroll
    for (int off = 32; off > 0; off >>= 1) prod += __shfl_down(prod, off);
    if (j == 0) out[g] = prod + lb2[0];
}

extern "C" void kernel_launch(void* const* d_in, const int* in_sizes, int n_in,
                              void* d_out, int out_size, void* d_ws, size_t ws_size,
                              hipStream_t stream) {
    const float* x   = (const float*)d_in[0];
    const int*   ei  = (const int*)d_in[1];
    const int*   bat = (const int*)d_in[2];
    const float* W1  = (const float*)d_in[3];
    const float* b1  = (const float*)d_in[4];
    const float* W2  = (const float*)d_in[5];
    const float* b2  = (const float*)d_in[6];
    const float* W3  = (const float*)d_in[7];
    const float* b3  = (const float*)d_in[8];
    const float* lw1 = (const float*)d_in[9];
    const float* lb1 = (const float*)d_in[10];
    const float* lw2 = (const float*)d_in[11];
    const float* lb2 = (const float*)d_in[12];
    float* out = (float*)d_out;

    const int nN = in_sizes[2];       // 100000
    const int nE = in_sizes[1] / 2;   // 3200000
    const int G  = out_size;          // 4096
    const int* src = ei;
    const int* dst = ei + nE;

    const int nbins = (nN + (1 << BIN_SHIFT) - 1) >> BIN_SHIFT;  // 391 (<=512)
    const size_t capTotal = (size_t)nbins << CAP_SHIFT;          // 6.4M slots

    // workspace layout
    char* p = (char*)d_ws;
    auto alloc = [&](size_t bytes) { char* r = p; p += (bytes + 255) & ~(size_t)255; return r; };
    unsigned* act16     = (unsigned*)alloc(sizeof(unsigned) * (size_t)nN * 64);
    unsigned* h16       = (unsigned*)alloc(sizeof(unsigned) * ((size_t)nN * 64 > capTotal ? (size_t)nN * 64 : capTotal));
    float*    dinv      = (float*)alloc(sizeof(float) * nN);
    float*    sums      = (float*)alloc(sizeof(float) * (size_t)G * HID);
    float*    cnt       = (float*)alloc(sizeof(float) * G);
    int*      bin_cur   = (int*)alloc(sizeof(int) * (nbins + 1));
    int*      row_start = (int*)alloc(sizeof(int) * nN);
    int*      row_end   = (int*)alloc(sizeof(int) * nN);
    int*      esrc      = (int*)alloc(sizeof(int) * capTotal);
    unsigned* staged    = (unsigned*)h16;  // consumed by k_place2 before gemm writes h16

    const int gemmGrid = (nN + 63) / 64;
    const int aggGrid  = (int)(((long long)nN * 64 + 255) / 256);
    const int edgeWGs  = (int)(((long long)nE + 4095) / 4096);

    // ---- CSR build (fixed-capacity bins) ----
    k_initcur<<<(nbins + 255) / 256, 256, 0, stream>>>(bin_cur, nbins);
    k_stage<<<edgeWGs, 256, 0, stream>>>(src, dst, bin_cur, staged, nE, nbins);
    k_place2<<<nbins, 256, 0, stream>>>(bin_cur, staged, esrc, row_start, row_end, dinv, nN);

    // ---- pooling denominators ----
    hipMemsetAsync(sums, 0, sizeof(float) * ((size_t)G * HID + G), stream);
    k_count<<<(nN + 255) / 256, 256, 0, stream>>>(bat, cnt, nN);

    // ---- 3 GCN layers (MFMA GEMM + gather-agg) ----
    k_gemm_mfma<true ><<<gemmGrid, 256, 0, stream>>>(x, W1, dinv, h16, nN);
    k_agg16<<<aggGrid, 256, 0, stream>>>(row_start, row_end, esrc, dinv, h16, b1, act16, nN, nullptr, nullptr);
    k_gemm_mfma<false><<<gemmGrid, 256, 0, stream>>>(act16, W2, dinv, h16, nN);
    k_agg16<<<aggGrid, 256, 0, stream>>>(row_start, row_end, esrc, dinv, h16, b2, act16, nN, nullptr, nullptr);
    k_gemm_mfma<false><<<gemmGrid, 256, 0, stream>>>(act16, W3, dinv, h16, nN);
    k_agg16<<<aggGrid, 256, 0, stream>>>(row_start, row_end, esrc, dinv, h16, b3, nullptr, nN, sums, bat);

    // ---- head ----
    k_mlp<<<G, 64, 0, stream>>>(sums, cnt, lw1, lb1, lw2, lb2, out);
}